// Round 6
// baseline (345.290 us; speedup 1.0000x reference)
//
#include <hip/hip_runtime.h>
#include <math.h>

#define NEG_SLOPE 0.2f

typedef __attribute__((ext_vector_type(8))) short short8;
typedef __attribute__((ext_vector_type(4))) float f32x4;

__device__ __forceinline__ float leaky(float x) { return x > 0.f ? x : NEG_SLOPE * x; }

// fp32 -> bf16 (RNE)
__device__ __forceinline__ short f2bf(float f) {
    union { float f; unsigned u; } v; v.f = f;
    unsigned r = v.u + 0x7fffu + ((v.u >> 16) & 1u);
    return (short)(r >> 16);
}
__device__ __forceinline__ float bf2f(unsigned short s) {
    union { unsigned u; float f; } v; v.u = ((unsigned)s) << 16;
    return v.f;
}
// unpack a dword holding two bf16 (lo = even col, hi = odd col)
__device__ __forceinline__ void unpack2(unsigned v, float& lo, float& hi) {
    union { unsigned u; float f; } a, b;
    a.u = v << 16; b.u = v & 0xffff0000u;
    lo = a.f; hi = b.f;
}

// ================= CSR build: workgroup-exclusive counting sort =================
#define GCHUNK 256
#define NB_MAX 1024   // supports N <= 131072

__global__ __launch_bounds__(256) void hist_kernel(const int* __restrict__ dst, int E, int nbuck,
                                                   int* __restrict__ histG, int* __restrict__ total) {
    __shared__ int lh[NB_MAX];
    int g = blockIdx.x, t = threadIdx.x;
    for (int i = t; i < nbuck; i += 256) lh[i] = 0;
    __syncthreads();
    int ce = (E + GCHUNK - 1) / GCHUNK;
    int e0 = g * ce, e1 = min(e0 + ce, E);
    for (int e = e0 + t; e < e1; e += 256)
        atomicAdd(&lh[dst[e] >> 7], 1);
    __syncthreads();
    for (int i = t; i < nbuck; i += 256) {
        histG[i * GCHUNK + g] = lh[i];
        if (lh[i]) atomicAdd(&total[i], lh[i]);
    }
}

__global__ __launch_bounds__(1024) void bscan_kernel(const int* __restrict__ total,
                                                     int* __restrict__ bbase, int nbuck) {
    __shared__ int sh[1024];
    int t = threadIdx.x;
    int v = (t < nbuck) ? total[t] : 0;
    sh[t] = v; __syncthreads();
    for (int s = 1; s < 1024; s <<= 1) {
        int add = (t >= s) ? sh[t - s] : 0;
        __syncthreads();
        sh[t] += add;
        __syncthreads();
    }
    if (t < nbuck) bbase[t] = sh[t] - v;
    if (t == nbuck - 1) bbase[nbuck] = sh[t];
}

__global__ __launch_bounds__(256) void bstart_kernel(const int* __restrict__ histG,
                                                     const int* __restrict__ bbase,
                                                     int* __restrict__ startG, int nbuck) {
    __shared__ int sh[256];
    int b = blockIdx.x, t = threadIdx.x;
    int v = histG[b * GCHUNK + t];
    sh[t] = v; __syncthreads();
    for (int s = 1; s < 256; s <<= 1) {
        int add = (t >= s) ? sh[t - s] : 0;
        __syncthreads();
        sh[t] += add;
        __syncthreads();
    }
    startG[b * GCHUNK + t] = bbase[b] + sh[t] - v;
}

__global__ __launch_bounds__(256) void bucket_scatter(const int* __restrict__ src,
                                                      const int* __restrict__ dst, int E, int nbuck,
                                                      const int* __restrict__ startG,
                                                      int* __restrict__ pairbuf) {
    __shared__ int cur[NB_MAX];
    int g = blockIdx.x, t = threadIdx.x;
    for (int i = t; i < nbuck; i += 256) cur[i] = startG[i * GCHUNK + g];
    __syncthreads();
    int ce = (E + GCHUNK - 1) / GCHUNK;
    int e0 = g * ce, e1 = min(e0 + ce, E);
    for (int e = e0 + t; e < e1; e += 256) {
        int d = dst[e], b = d >> 7;
        int pos = atomicAdd(&cur[b], 1);
        pairbuf[pos] = (src[e] << 7) | (d & 127);
    }
}

__global__ __launch_bounds__(256) void bucket_place(const int* __restrict__ pairbuf,
                                                    const int* __restrict__ bbase, int nbuck, int N,
                                                    int* __restrict__ deg, int* __restrict__ off,
                                                    int* __restrict__ csr) {
    __shared__ int stash[4096];
    __shared__ int ldeg[128], lcur[128], sh[128];
    int b = blockIdx.x, t = threadIdx.x;
    int p0 = bbase[b], p1 = bbase[b + 1];
    int cnt = p1 - p0;
    int node0 = b << 7;
    for (int i = t; i < 128; i += 256) ldeg[i] = 0;
    __syncthreads();
    for (int i = t; i < cnt; i += 256) {
        int pr = pairbuf[p0 + i];
        if (i < 4096) stash[i] = pr;
        atomicAdd(&ldeg[pr & 127], 1);
    }
    __syncthreads();
    if (t < 128) sh[t] = ldeg[t];
    __syncthreads();
    for (int s = 1; s < 128; s <<= 1) {
        int add = (t >= s && t < 128) ? sh[t - s] : 0;
        __syncthreads();
        if (t < 128) sh[t] += add;
        __syncthreads();
    }
    if (t < 128) {
        int excl = sh[t] - ldeg[t];
        int n = node0 + t;
        if (n < N) { deg[n] = ldeg[t]; off[n] = p0 + excl; }
        lcur[t] = p0 + excl;
    }
    __syncthreads();
    for (int i = t; i < cnt; i += 256) {
        int pr = (i < 4096) ? stash[i] : pairbuf[p0 + i];
        int pos = atomicAdd(&lcur[pr & 127], 1);
        csr[pos] = ((unsigned)pr) >> 7;
    }
}

// ---------------- GEMM1 (MFMA): h1 = bf16(x @ W1), dots in fp32 ----------------
__global__ __launch_bounds__(256) void gemm1_mfma(
    const float* __restrict__ x, const float* __restrict__ W1,
    const float* __restrict__ att_src, const float* __restrict__ att_dst,
    unsigned short* __restrict__ h1, float* __restrict__ a_src, float* __restrict__ a_dst, int N)
{
    __shared__ short Bl[16 * 64 * 8];   // 16 B-frags (ct,s), 16 KB
    __shared__ float Cs[4][32 * 64];    // fp32 C stage, 32 KB
    int tid = threadIdx.x;
    for (int f0 = tid; f0 < 1024; f0 += 256) {
        int lane = f0 & 63, s = (f0 >> 6) & 3, ct = f0 >> 8;
        int kb = s * 32 + ((lane >> 4) << 3);
        int col = ct * 16 + (lane & 15);
        short* dp = &Bl[f0 * 8];
#pragma unroll
        for (int j = 0; j < 8; ++j) dp[j] = f2bf(W1[(kb + j) * 64 + col]);
    }
    __syncthreads();

    int lane = tid & 63, w = tid >> 6;
    int row0 = blockIdx.x * 128 + w * 32;
    int ra = min(row0 + (lane & 15), N - 1);
    int rb = min(row0 + 16 + (lane & 15), N - 1);
    const float* pa = x + (size_t)ra * 128 + ((lane >> 4) << 3);
    const float* pb = x + (size_t)rb * 128 + ((lane >> 4) << 3);

    f32x4 acc[2][4];
#pragma unroll
    for (int i = 0; i < 2; ++i)
#pragma unroll
        for (int j = 0; j < 4; ++j) acc[i][j] = (f32x4){0.f, 0.f, 0.f, 0.f};

#pragma unroll
    for (int s = 0; s < 4; ++s) {
        float4 a0 = *(const float4*)(pa + s * 32);
        float4 a1 = *(const float4*)(pa + s * 32 + 4);
        float4 c0 = *(const float4*)(pb + s * 32);
        float4 c1 = *(const float4*)(pb + s * 32 + 4);
        short8 af, cf;
        af[0] = f2bf(a0.x); af[1] = f2bf(a0.y); af[2] = f2bf(a0.z); af[3] = f2bf(a0.w);
        af[4] = f2bf(a1.x); af[5] = f2bf(a1.y); af[6] = f2bf(a1.z); af[7] = f2bf(a1.w);
        cf[0] = f2bf(c0.x); cf[1] = f2bf(c0.y); cf[2] = f2bf(c0.z); cf[3] = f2bf(c0.w);
        cf[4] = f2bf(c1.x); cf[5] = f2bf(c1.y); cf[6] = f2bf(c1.z); cf[7] = f2bf(c1.w);
#pragma unroll
        for (int ct = 0; ct < 4; ++ct) {
            short8 wf = *(const short8*)&Bl[((ct * 4 + s) * 64 + lane) * 8];
            acc[0][ct] = __builtin_amdgcn_mfma_f32_16x16x32_bf16(af, wf, acc[0][ct], 0, 0, 0);
            acc[1][ct] = __builtin_amdgcn_mfma_f32_16x16x32_bf16(cf, wf, acc[1][ct], 0, 0, 0);
        }
    }

    float* cs = &Cs[w][0];
#pragma unroll
    for (int rt = 0; rt < 2; ++rt)
#pragma unroll
        for (int ct = 0; ct < 4; ++ct)
#pragma unroll
            for (int r = 0; r < 4; ++r) {
                int row = rt * 16 + ((lane >> 4) << 2) + r;
                int col = ct * 16 + (lane & 15);
                cs[row * 64 + col] = acc[rt][ct][r];
            }
    __syncthreads();

    float asv = att_src[lane], adv = att_dst[lane];
    for (int r = 0; r < 32; ++r) {
        int row = row0 + r;
        float v = cs[r * 64 + lane];
        float ts = v * asv, td = v * adv;
        ts += __shfl_xor(ts, 1); ts += __shfl_xor(ts, 2); ts += __shfl_xor(ts, 4);
        td += __shfl_xor(td, 1); td += __shfl_xor(td, 2); td += __shfl_xor(td, 4);
        if (row < N) {
            h1[(size_t)row * 64 + lane] = (unsigned short)f2bf(v);
            if ((lane & 7) == 0) {
                a_src[row * 8 + (lane >> 3)] = ts;
                a_dst[row * 8 + (lane >> 3)] = td;
            }
        }
    }
}

// ---------------- layer-1 aggregate: quad-col layout, 4 edges per load ----------------
// lane = (grp = lane>>4 : edge-in-quad, k = lane&15 : col-quad -> cols 4k..4k+3)
// A 4-col quad never crosses an 8-col head boundary: head(k) = k>>1.
// p (per edge per head) staged in a per-wave LDS region; no barriers needed.
__global__ __launch_bounds__(256) void agg1_kernel(
    const unsigned short* __restrict__ h1, const float* __restrict__ a_src, const float* __restrict__ a_dst,
    const int* __restrict__ off, const int* __restrict__ deg, const int* __restrict__ csr,
    const float* __restrict__ b1, unsigned short* __restrict__ helu, int N)
{
    __shared__ float lds_p[4][512];
    int tid = threadIdx.x;
    int n = (blockIdx.x * 256 + tid) >> 6;
    int lane = tid & 63;
    if (n >= N) return;
    float* myp = &lds_p[tid >> 6][0];
    int o = off[n], d = deg[n];
    int h8 = lane & 7, g = lane >> 3;
    int k = lane & 15, grp = lane >> 4;

    float adst = a_dst[n * 8 + h8];
    float pself = __expf(leaky(a_src[n * 8 + h8] + adst));  // lane L holds pself[L&7]
    float s = (g == 0) ? pself : 0.f;

    // self loop (quad-col layout); only grp 0 contributes
    float aself = (grp == 0) ? __shfl(pself, k >> 1) : 0.f;
    uint2 dself = *(const uint2*)(h1 + (size_t)n * 64 + k * 4);
    float f0, f1, f2, f3;
    unpack2(dself.x, f0, f1);
    unpack2(dself.y, f2, f3);
    float acc0 = aself * f0, acc1 = aself * f1, acc2 = aself * f2, acc3 = aself * f3;

    for (int base = 0; base < d; base += 64) {
        int idx = base + lane;
        int sv = (idx < d) ? csr[o + idx] : 0;
        int lim = min(64, d - base);
        int tmax = (lim + 7) >> 3;
        // p-pass: 8 edges/iter, lane computes p[edge t*8+g][head h8], stages to LDS
        for (int t = 0; t < tmax; ++t) {
            int eidx = t * 8 + g;
            int srcn = __shfl(sv, eidx);
            float p = 0.f;
            if (eidx < lim) p = __expf(leaky(a_src[srcn * 8 + h8] + adst));
            s += p;
            myp[t * 64 + lane] = p;   // = p[eidx*8 + h8]
        }
        // feature pass: 4 edges/iter; one dwordx2 load serves 4 rows
        int imax = (lim + 3) >> 2;
        for (int i = 0; i < imax; ++i) {
            int e = i * 4 + grp;
            int se = __shfl(sv, e);
            float al = myp[e * 8 + (k >> 1)];
            uint2 dv = *(const uint2*)(h1 + (size_t)se * 64 + k * 4);
            float g0, g1, g2, g3;
            unpack2(dv.x, g0, g1);
            unpack2(dv.y, g2, g3);
            acc0 = fmaf(al, g0, acc0);
            acc1 = fmaf(al, g1, acc1);
            acc2 = fmaf(al, g2, acc2);
            acc3 = fmaf(al, g3, acc3);
        }
    }
    // denominator per head
    s += __shfl_xor(s, 8); s += __shfl_xor(s, 16); s += __shfl_xor(s, 32);
    // reduce acc across the 4 edge groups
    acc0 += __shfl_xor(acc0, 16); acc1 += __shfl_xor(acc1, 16);
    acc2 += __shfl_xor(acc2, 16); acc3 += __shfl_xor(acc3, 16);
    acc0 += __shfl_xor(acc0, 32); acc1 += __shfl_xor(acc1, 32);
    acc2 += __shfl_xor(acc2, 32); acc3 += __shfl_xor(acc3, 32);
    float sH = __shfl(s, k >> 1);
    if (grp == 0) {
        float r = 1.f / sH;
        float4 bv = *(const float4*)(b1 + k * 4);
        float v0 = acc0 * r + bv.x, v1 = acc1 * r + bv.y;
        float v2 = acc2 * r + bv.z, v3 = acc3 * r + bv.w;
        v0 = (v0 > 0.f) ? v0 : (__expf(v0) - 1.f);
        v1 = (v1 > 0.f) ? v1 : (__expf(v1) - 1.f);
        v2 = (v2 > 0.f) ? v2 : (__expf(v2) - 1.f);
        v3 = (v3 > 0.f) ? v3 : (__expf(v3) - 1.f);
        uint2 st;
        st.x = ((unsigned)(unsigned short)f2bf(v0)) | (((unsigned)(unsigned short)f2bf(v1)) << 16);
        st.y = ((unsigned)(unsigned short)f2bf(v2)) | (((unsigned)(unsigned short)f2bf(v3)) << 16);
        *(uint2*)(helu + (size_t)n * 64 + k * 4) = st;
    }
}

// -------- GEMM2 (MFMA): h2p = bf16(helu @ W2), rows PADDED to 64 cols --------
__global__ __launch_bounds__(256) void gemm2_mfma(
    const unsigned short* __restrict__ hin, const float* __restrict__ W2,
    const float* __restrict__ att_src2, const float* __restrict__ att_dst2,
    unsigned short* __restrict__ h2p, float* __restrict__ a_src, float* __restrict__ a_dst, int N)
{
    __shared__ short Bl[6 * 64 * 8];
    __shared__ float Cs[4][32 * 48];
    int tid = threadIdx.x;
    for (int f0 = tid; f0 < 384; f0 += 256) {
        int lane = f0 & 63; int fr = f0 >> 6; int s = fr & 1, ct = fr >> 1;
        int kb = s * 32 + ((lane >> 4) << 3);
        int col = ct * 16 + (lane & 15);
        short* dp = &Bl[f0 * 8];
#pragma unroll
        for (int j = 0; j < 8; ++j) dp[j] = (col < 40) ? f2bf(W2[(kb + j) * 40 + col]) : (short)0;
    }
    __syncthreads();

    int lane = tid & 63, w = tid >> 6;
    int row0 = blockIdx.x * 128 + w * 32;
    int ra = min(row0 + (lane & 15), N - 1);
    int rb = min(row0 + 16 + (lane & 15), N - 1);
    const unsigned short* pa = hin + (size_t)ra * 64 + ((lane >> 4) << 3);
    const unsigned short* pb = hin + (size_t)rb * 64 + ((lane >> 4) << 3);

    f32x4 acc[2][3];
#pragma unroll
    for (int i = 0; i < 2; ++i)
#pragma unroll
        for (int j = 0; j < 3; ++j) acc[i][j] = (f32x4){0.f, 0.f, 0.f, 0.f};

#pragma unroll
    for (int s = 0; s < 2; ++s) {
        short8 af = *(const short8*)(pa + s * 32);
        short8 cf = *(const short8*)(pb + s * 32);
#pragma unroll
        for (int ct = 0; ct < 3; ++ct) {
            short8 wf = *(const short8*)&Bl[((ct * 2 + s) * 64 + lane) * 8];
            acc[0][ct] = __builtin_amdgcn_mfma_f32_16x16x32_bf16(af, wf, acc[0][ct], 0, 0, 0);
            acc[1][ct] = __builtin_amdgcn_mfma_f32_16x16x32_bf16(cf, wf, acc[1][ct], 0, 0, 0);
        }
    }

    float* cs = &Cs[w][0];
#pragma unroll
    for (int rt = 0; rt < 2; ++rt)
#pragma unroll
        for (int ct = 0; ct < 3; ++ct)
#pragma unroll
            for (int r = 0; r < 4; ++r) {
                int row = rt * 16 + ((lane >> 4) << 2) + r;
                int col = ct * 16 + (lane & 15);
                cs[row * 48 + col] = acc[rt][ct][r];
            }
    __syncthreads();

    float asv = (lane < 40) ? att_src2[lane] : 0.f;
    float adv = (lane < 40) ? att_dst2[lane] : 0.f;
    for (int r = 0; r < 32; ++r) {
        int row = row0 + r;
        float v = (lane < 48) ? cs[r * 48 + lane] : 0.f;
        float ts = (lane < 40) ? v * asv : 0.f;
        float td = (lane < 40) ? v * adv : 0.f;
        for (int st = 1; st < 64; st <<= 1) { ts += __shfl_xor(ts, st); td += __shfl_xor(td, st); }
        if (row < N) {
            h2p[(size_t)row * 64 + lane] = (unsigned short)f2bf(v);  // padded row
            if (lane == 0) { a_src[row] = ts; a_dst[row] = td; }
        }
    }
}

// ---------------- layer-2 aggregate (quad-col layout) + bias + log_softmax ----------------
__global__ __launch_bounds__(256) void agg2_kernel(
    const unsigned short* __restrict__ h2p, const float* __restrict__ a_src, const float* __restrict__ a_dst,
    const int* __restrict__ off, const int* __restrict__ deg, const int* __restrict__ csr,
    const float* __restrict__ b2, float* __restrict__ out, int N)
{
    int tid = threadIdx.x;
    int n = (blockIdx.x * 256 + tid) >> 6;
    int lane = tid & 63;
    if (n >= N) return;
    int o = off[n], d = deg[n];
    int k = lane & 15, grp = lane >> 4;

    float adst = a_dst[n];
    float pself = __expf(leaky(a_src[n] + adst));
    float sp = 0.f;

    float aself = (grp == 0) ? pself : 0.f;
    uint2 dself = *(const uint2*)(h2p + (size_t)n * 64 + k * 4);
    float f0, f1, f2, f3;
    unpack2(dself.x, f0, f1);
    unpack2(dself.y, f2, f3);
    float acc0 = aself * f0, acc1 = aself * f1, acc2 = aself * f2, acc3 = aself * f3;

    for (int base = 0; base < d; base += 64) {
        int idx = base + lane;
        int sv = (idx < d) ? csr[o + idx] : 0;
        float pv = 0.f;
        if (idx < d) pv = __expf(leaky(a_src[sv] + adst));
        sp += pv;
        int lim = min(64, d - base);
        int imax = (lim + 3) >> 2;
        for (int i = 0; i < imax; ++i) {
            int e = i * 4 + grp;
            int se = __shfl(sv, e);
            float al = __shfl(pv, e);     // pv=0 for e>=lim masks OOB edges
            uint2 dv = *(const uint2*)(h2p + (size_t)se * 64 + k * 4);
            float g0, g1, g2, g3;
            unpack2(dv.x, g0, g1);
            unpack2(dv.y, g2, g3);
            acc0 = fmaf(al, g0, acc0);
            acc1 = fmaf(al, g1, acc1);
            acc2 = fmaf(al, g2, acc2);
            acc3 = fmaf(al, g3, acc3);
        }
    }
    for (int st = 1; st < 64; st <<= 1) sp += __shfl_xor(sp, st);
    float stot = sp + pself;

    acc0 += __shfl_xor(acc0, 16); acc1 += __shfl_xor(acc1, 16);
    acc2 += __shfl_xor(acc2, 16); acc3 += __shfl_xor(acc3, 16);
    acc0 += __shfl_xor(acc0, 32); acc1 += __shfl_xor(acc1, 32);
    acc2 += __shfl_xor(acc2, 32); acc3 += __shfl_xor(acc3, 32);

    // lanes grp==0, k<10 hold the 40 valid cols (4 each)
    bool valid = (grp == 0) && (k < 10);
    float r = 1.f / stot;
    float v0 = -INFINITY, v1 = -INFINITY, v2 = -INFINITY, v3 = -INFINITY;
    if (valid) {
        float4 bv = *(const float4*)(b2 + k * 4);
        v0 = acc0 * r + bv.x; v1 = acc1 * r + bv.y;
        v2 = acc2 * r + bv.z; v3 = acc3 * r + bv.w;
    }
    float mx = fmaxf(fmaxf(v0, v1), fmaxf(v2, v3));
    for (int st = 1; st < 64; st <<= 1) mx = fmaxf(mx, __shfl_xor(mx, st));
    float se = 0.f;
    if (valid)
        se = __expf(v0 - mx) + __expf(v1 - mx) + __expf(v2 - mx) + __expf(v3 - mx);
    for (int st = 1; st < 64; st <<= 1) se += __shfl_xor(se, st);
    if (valid) {
        float ls = mx + logf(se);
        float4 ov = make_float4(v0 - ls, v1 - ls, v2 - ls, v3 - ls);
        *(float4*)(out + (size_t)n * 40 + k * 4) = ov;
    }
}

extern "C" void kernel_launch(void* const* d_in, const int* in_sizes, int n_in,
                              void* d_out, int out_size, void* d_ws, size_t ws_size,
                              hipStream_t stream) {
    const float* x        = (const float*)d_in[0];
    const int*   ei       = (const int*)d_in[1];
    const float* W1       = (const float*)d_in[2];
    const float* att_src1 = (const float*)d_in[3];
    const float* att_dst1 = (const float*)d_in[4];
    const float* b1       = (const float*)d_in[5];
    const float* W2       = (const float*)d_in[6];
    const float* att_src2 = (const float*)d_in[7];
    const float* att_dst2 = (const float*)d_in[8];
    const float* b2       = (const float*)d_in[9];
    float* out = (float*)d_out;

    int N = in_sizes[0] / 128;
    int E = in_sizes[1] / 2;
    const int* src = ei;
    const int* dst = ei + E;
    int nbuck = (N + 127) >> 7;

    char* w = (char*)d_ws;
    auto alloc = [&](size_t bytes) { void* p = (void*)w; w += (bytes + 255) & ~(size_t)255; return p; };
    unsigned short* h1   = (unsigned short*)alloc((size_t)N * 64 * 2);
    unsigned short* helu = (unsigned short*)alloc((size_t)N * 64 * 2);
    float* as1  = (float*)alloc((size_t)N * 8 * 4);
    float* ad1  = (float*)alloc((size_t)N * 8 * 4);
    int*   degv = (int*)alloc((size_t)N * 4);
    int*   offv = (int*)alloc((size_t)(N + 1) * 4);
    int*   csr  = (int*)alloc((size_t)E * 4);
    int*   histG  = (int*)alloc((size_t)nbuck * GCHUNK * 4);
    int*   startG = (int*)alloc((size_t)nbuck * GCHUNK * 4);
    int*   total  = (int*)alloc((size_t)nbuck * 4);
    int*   bbase  = (int*)alloc((size_t)(nbuck + 1) * 4);
    int*   pairbuf = (int*)alloc((size_t)E * 4);
    unsigned short* h2p = h1;   // reuse: h1 dead after agg1
    float* as2 = as1;
    float* ad2 = ad1;

    hipMemsetAsync(total, 0, (size_t)nbuck * 4, stream);
    hist_kernel<<<GCHUNK, 256, 0, stream>>>(dst, E, nbuck, histG, total);
    bscan_kernel<<<1, 1024, 0, stream>>>(total, bbase, nbuck);
    bstart_kernel<<<nbuck, 256, 0, stream>>>(histG, bbase, startG, nbuck);
    bucket_scatter<<<GCHUNK, 256, 0, stream>>>(src, dst, E, nbuck, startG, pairbuf);
    bucket_place<<<nbuck, 256, 0, stream>>>(pairbuf, bbase, nbuck, N, degv, offv, csr);

    int gb = (N + 127) / 128;
    gemm1_mfma<<<gb, 256, 0, stream>>>(x, W1, att_src1, att_dst1, h1, as1, ad1, N);
    agg1_kernel<<<(N + 3) / 4, 256, 0, stream>>>(h1, as1, ad1, offv, degv, csr, b1, helu, N);
    gemm2_mfma<<<gb, 256, 0, stream>>>(helu, W2, att_src2, att_dst2, h2p, as2, ad2, N);
    agg2_kernel<<<(N + 3) / 4, 256, 0, stream>>>(h2p, as2, ad2, offv, degv, csr, b2, out, N);
}

// Round 7
// 327.500 us; speedup vs baseline: 1.0543x; 1.0543x over previous
//
#include <hip/hip_runtime.h>
#include <math.h>

#define NEG_SLOPE 0.2f

typedef __attribute__((ext_vector_type(8))) short short8;
typedef __attribute__((ext_vector_type(4))) float f32x4;

__device__ __forceinline__ float leaky(float x) { return x > 0.f ? x : NEG_SLOPE * x; }

// fp32 -> bf16 (RNE)
__device__ __forceinline__ short f2bf(float f) {
    union { float f; unsigned u; } v; v.f = f;
    unsigned r = v.u + 0x7fffu + ((v.u >> 16) & 1u);
    return (short)(r >> 16);
}
__device__ __forceinline__ float bf2f(unsigned short s) {
    union { unsigned u; float f; } v; v.u = ((unsigned)s) << 16;
    return v.f;
}
// unpack a dword holding two bf16 (lo = even col, hi = odd col)
__device__ __forceinline__ void unpack2(unsigned v, float& lo, float& hi) {
    union { unsigned u; float f; } a, b;
    a.u = v << 16; b.u = v & 0xffff0000u;
    lo = a.f; hi = b.f;
}

// ================= CSR build: workgroup-exclusive counting sort =================
#define GCHUNK 256
#define NB_MAX 1024   // supports N <= 131072

__global__ __launch_bounds__(256) void hist_kernel(const int* __restrict__ dst, int E, int nbuck,
                                                   int* __restrict__ histG, int* __restrict__ total) {
    __shared__ int lh[NB_MAX];
    int g = blockIdx.x, t = threadIdx.x;
    for (int i = t; i < nbuck; i += 256) lh[i] = 0;
    __syncthreads();
    int ce = (E + GCHUNK - 1) / GCHUNK;
    int e0 = g * ce, e1 = min(e0 + ce, E);
    for (int e = e0 + t; e < e1; e += 256)
        atomicAdd(&lh[dst[e] >> 7], 1);
    __syncthreads();
    for (int i = t; i < nbuck; i += 256) {
        histG[i * GCHUNK + g] = lh[i];
        if (lh[i]) atomicAdd(&total[i], lh[i]);
    }
}

__global__ __launch_bounds__(1024) void bscan_kernel(const int* __restrict__ total,
                                                     int* __restrict__ bbase, int nbuck) {
    __shared__ int sh[1024];
    int t = threadIdx.x;
    int v = (t < nbuck) ? total[t] : 0;
    sh[t] = v; __syncthreads();
    for (int s = 1; s < 1024; s <<= 1) {
        int add = (t >= s) ? sh[t - s] : 0;
        __syncthreads();
        sh[t] += add;
        __syncthreads();
    }
    if (t < nbuck) bbase[t] = sh[t] - v;
    if (t == nbuck - 1) bbase[nbuck] = sh[t];
}

__global__ __launch_bounds__(256) void bstart_kernel(const int* __restrict__ histG,
                                                     const int* __restrict__ bbase,
                                                     int* __restrict__ startG, int nbuck) {
    __shared__ int sh[256];
    int b = blockIdx.x, t = threadIdx.x;
    int v = histG[b * GCHUNK + t];
    sh[t] = v; __syncthreads();
    for (int s = 1; s < 256; s <<= 1) {
        int add = (t >= s) ? sh[t - s] : 0;
        __syncthreads();
        sh[t] += add;
        __syncthreads();
    }
    startG[b * GCHUNK + t] = bbase[b] + sh[t] - v;
}

__global__ __launch_bounds__(256) void bucket_scatter(const int* __restrict__ src,
                                                      const int* __restrict__ dst, int E, int nbuck,
                                                      const int* __restrict__ startG,
                                                      int* __restrict__ pairbuf) {
    __shared__ int cur[NB_MAX];
    int g = blockIdx.x, t = threadIdx.x;
    for (int i = t; i < nbuck; i += 256) cur[i] = startG[i * GCHUNK + g];
    __syncthreads();
    int ce = (E + GCHUNK - 1) / GCHUNK;
    int e0 = g * ce, e1 = min(e0 + ce, E);
    for (int e = e0 + t; e < e1; e += 256) {
        int d = dst[e], b = d >> 7;
        int pos = atomicAdd(&cur[b], 1);
        pairbuf[pos] = (src[e] << 7) | (d & 127);
    }
}

__global__ __launch_bounds__(256) void bucket_place(const int* __restrict__ pairbuf,
                                                    const int* __restrict__ bbase, int nbuck, int N,
                                                    int* __restrict__ deg, int* __restrict__ off,
                                                    int* __restrict__ csr) {
    __shared__ int stash[4096];
    __shared__ int ldeg[128], lcur[128], sh[128];
    int b = blockIdx.x, t = threadIdx.x;
    int p0 = bbase[b], p1 = bbase[b + 1];
    int cnt = p1 - p0;
    int node0 = b << 7;
    for (int i = t; i < 128; i += 256) ldeg[i] = 0;
    __syncthreads();
    for (int i = t; i < cnt; i += 256) {
        int pr = pairbuf[p0 + i];
        if (i < 4096) stash[i] = pr;
        atomicAdd(&ldeg[pr & 127], 1);
    }
    __syncthreads();
    if (t < 128) sh[t] = ldeg[t];
    __syncthreads();
    for (int s = 1; s < 128; s <<= 1) {
        int add = (t >= s && t < 128) ? sh[t - s] : 0;
        __syncthreads();
        if (t < 128) sh[t] += add;
        __syncthreads();
    }
    if (t < 128) {
        int excl = sh[t] - ldeg[t];
        int n = node0 + t;
        if (n < N) { deg[n] = ldeg[t]; off[n] = p0 + excl; }
        lcur[t] = p0 + excl;
    }
    __syncthreads();
    for (int i = t; i < cnt; i += 256) {
        int pr = (i < 4096) ? stash[i] : pairbuf[p0 + i];
        int pos = atomicAdd(&lcur[pr & 127], 1);
        csr[pos] = ((unsigned)pr) >> 7;
    }
}

// ---------------- GEMM1 (MFMA): h1 = bf16(x @ W1), dots in fp32 ----------------
__global__ __launch_bounds__(256) void gemm1_mfma(
    const float* __restrict__ x, const float* __restrict__ W1,
    const float* __restrict__ att_src, const float* __restrict__ att_dst,
    unsigned short* __restrict__ h1, float* __restrict__ a_src, float* __restrict__ a_dst, int N)
{
    __shared__ short Bl[16 * 64 * 8];   // 16 B-frags (ct,s), 16 KB
    __shared__ float Cs[4][32 * 64];    // fp32 C stage, 32 KB
    int tid = threadIdx.x;
    for (int f0 = tid; f0 < 1024; f0 += 256) {
        int lane = f0 & 63, s = (f0 >> 6) & 3, ct = f0 >> 8;
        int kb = s * 32 + ((lane >> 4) << 3);
        int col = ct * 16 + (lane & 15);
        short* dp = &Bl[f0 * 8];
#pragma unroll
        for (int j = 0; j < 8; ++j) dp[j] = f2bf(W1[(kb + j) * 64 + col]);
    }
    __syncthreads();

    int lane = tid & 63, w = tid >> 6;
    int row0 = blockIdx.x * 128 + w * 32;
    int ra = min(row0 + (lane & 15), N - 1);
    int rb = min(row0 + 16 + (lane & 15), N - 1);
    const float* pa = x + (size_t)ra * 128 + ((lane >> 4) << 3);
    const float* pb = x + (size_t)rb * 128 + ((lane >> 4) << 3);

    f32x4 acc[2][4];
#pragma unroll
    for (int i = 0; i < 2; ++i)
#pragma unroll
        for (int j = 0; j < 4; ++j) acc[i][j] = (f32x4){0.f, 0.f, 0.f, 0.f};

#pragma unroll
    for (int s = 0; s < 4; ++s) {
        float4 a0 = *(const float4*)(pa + s * 32);
        float4 a1 = *(const float4*)(pa + s * 32 + 4);
        float4 c0 = *(const float4*)(pb + s * 32);
        float4 c1 = *(const float4*)(pb + s * 32 + 4);
        short8 af, cf;
        af[0] = f2bf(a0.x); af[1] = f2bf(a0.y); af[2] = f2bf(a0.z); af[3] = f2bf(a0.w);
        af[4] = f2bf(a1.x); af[5] = f2bf(a1.y); af[6] = f2bf(a1.z); af[7] = f2bf(a1.w);
        cf[0] = f2bf(c0.x); cf[1] = f2bf(c0.y); cf[2] = f2bf(c0.z); cf[3] = f2bf(c0.w);
        cf[4] = f2bf(c1.x); cf[5] = f2bf(c1.y); cf[6] = f2bf(c1.z); cf[7] = f2bf(c1.w);
#pragma unroll
        for (int ct = 0; ct < 4; ++ct) {
            short8 wf = *(const short8*)&Bl[((ct * 4 + s) * 64 + lane) * 8];
            acc[0][ct] = __builtin_amdgcn_mfma_f32_16x16x32_bf16(af, wf, acc[0][ct], 0, 0, 0);
            acc[1][ct] = __builtin_amdgcn_mfma_f32_16x16x32_bf16(cf, wf, acc[1][ct], 0, 0, 0);
        }
    }

    float* cs = &Cs[w][0];
#pragma unroll
    for (int rt = 0; rt < 2; ++rt)
#pragma unroll
        for (int ct = 0; ct < 4; ++ct)
#pragma unroll
            for (int r = 0; r < 4; ++r) {
                int row = rt * 16 + ((lane >> 4) << 2) + r;
                int col = ct * 16 + (lane & 15);
                cs[row * 64 + col] = acc[rt][ct][r];
            }
    __syncthreads();

    float asv = att_src[lane], adv = att_dst[lane];
    for (int r = 0; r < 32; ++r) {
        int row = row0 + r;
        float v = cs[r * 64 + lane];
        float ts = v * asv, td = v * adv;
        ts += __shfl_xor(ts, 1); ts += __shfl_xor(ts, 2); ts += __shfl_xor(ts, 4);
        td += __shfl_xor(td, 1); td += __shfl_xor(td, 2); td += __shfl_xor(td, 4);
        if (row < N) {
            h1[(size_t)row * 64 + lane] = (unsigned short)f2bf(v);
            if ((lane & 7) == 0) {
                a_src[row * 8 + (lane >> 3)] = ts;
                a_dst[row * 8 + (lane >> 3)] = td;
            }
        }
    }
}

// ---------------- layer-1 aggregate: merged single pass, octet layout ----------------
// lane = (g = lane>>3 : edge-in-octet, h8 = lane&7 : col-octet == head).
// The lane that computes p[edge][head h8] is the same lane that needs it as
// alpha for cols 8*h8..8*h8+7 -> no LDS, no broadcast. 8 edges per load instr,
// 2x unrolled => 4 independent loads in flight per lane.
__global__ __launch_bounds__(256) void agg1_kernel(
    const unsigned short* __restrict__ h1, const float* __restrict__ a_src, const float* __restrict__ a_dst,
    const int* __restrict__ off, const int* __restrict__ deg, const int* __restrict__ csr,
    const float* __restrict__ b1, unsigned short* __restrict__ helu, int N)
{
    int tid = threadIdx.x;
    int n = (blockIdx.x * 256 + tid) >> 6;
    int lane = tid & 63;
    if (n >= N) return;
    int o = off[n], d = deg[n];
    int h8 = lane & 7, g = lane >> 3;

    float adst = a_dst[n * 8 + h8];
    float pself = __expf(leaky(a_src[n * 8 + h8] + adst));
    float s = (g == 0) ? pself : 0.f;

    // self loop: alpha for head h8 (only group 0 contributes)
    float aself = (g == 0) ? __shfl(pself, h8) : 0.f;
    uint4 dvs = *(const uint4*)(h1 + (size_t)n * 64 + h8 * 8);
    float lo, hi;
    float acc0, acc1, acc2, acc3, acc4, acc5, acc6, acc7;
    unpack2(dvs.x, lo, hi); acc0 = aself * lo; acc1 = aself * hi;
    unpack2(dvs.y, lo, hi); acc2 = aself * lo; acc3 = aself * hi;
    unpack2(dvs.z, lo, hi); acc4 = aself * lo; acc5 = aself * hi;
    unpack2(dvs.w, lo, hi); acc6 = aself * lo; acc7 = aself * hi;

    for (int base = 0; base < d; base += 64) {
        int idx = base + lane;
        int sv = (idx < d) ? csr[o + idx] : 0;
        int lim = min(64, d - base);
        int tmax2 = (((lim + 7) >> 3) + 1) & ~1;   // even, <= 8
        for (int t = 0; t < tmax2; t += 2) {
            int e0 = t * 8 + g, e1 = e0 + 8;
            int s0 = __shfl(sv, e0), s1 = __shfl(sv, e1);
            // 4 independent loads issued back-to-back
            float as0 = a_src[s0 * 8 + h8];
            float as1 = a_src[s1 * 8 + h8];
            uint4 d0 = *(const uint4*)(h1 + (size_t)s0 * 64 + h8 * 8);
            uint4 d1 = *(const uint4*)(h1 + (size_t)s1 * 64 + h8 * 8);
            float p0 = (e0 < lim) ? __expf(leaky(as0 + adst)) : 0.f;
            float p1 = (e1 < lim) ? __expf(leaky(as1 + adst)) : 0.f;
            s += p0 + p1;
            unpack2(d0.x, lo, hi); acc0 = fmaf(p0, lo, acc0); acc1 = fmaf(p0, hi, acc1);
            unpack2(d0.y, lo, hi); acc2 = fmaf(p0, lo, acc2); acc3 = fmaf(p0, hi, acc3);
            unpack2(d0.z, lo, hi); acc4 = fmaf(p0, lo, acc4); acc5 = fmaf(p0, hi, acc5);
            unpack2(d0.w, lo, hi); acc6 = fmaf(p0, lo, acc6); acc7 = fmaf(p0, hi, acc7);
            unpack2(d1.x, lo, hi); acc0 = fmaf(p1, lo, acc0); acc1 = fmaf(p1, hi, acc1);
            unpack2(d1.y, lo, hi); acc2 = fmaf(p1, lo, acc2); acc3 = fmaf(p1, hi, acc3);
            unpack2(d1.z, lo, hi); acc4 = fmaf(p1, lo, acc4); acc5 = fmaf(p1, hi, acc5);
            unpack2(d1.w, lo, hi); acc6 = fmaf(p1, lo, acc6); acc7 = fmaf(p1, hi, acc7);
        }
    }
    // reduce over the 8 edge groups (flip g bits); h8 stays fixed
    s += __shfl_xor(s, 8); s += __shfl_xor(s, 16); s += __shfl_xor(s, 32);
    acc0 += __shfl_xor(acc0, 8); acc0 += __shfl_xor(acc0, 16); acc0 += __shfl_xor(acc0, 32);
    acc1 += __shfl_xor(acc1, 8); acc1 += __shfl_xor(acc1, 16); acc1 += __shfl_xor(acc1, 32);
    acc2 += __shfl_xor(acc2, 8); acc2 += __shfl_xor(acc2, 16); acc2 += __shfl_xor(acc2, 32);
    acc3 += __shfl_xor(acc3, 8); acc3 += __shfl_xor(acc3, 16); acc3 += __shfl_xor(acc3, 32);
    acc4 += __shfl_xor(acc4, 8); acc4 += __shfl_xor(acc4, 16); acc4 += __shfl_xor(acc4, 32);
    acc5 += __shfl_xor(acc5, 8); acc5 += __shfl_xor(acc5, 16); acc5 += __shfl_xor(acc5, 32);
    acc6 += __shfl_xor(acc6, 8); acc6 += __shfl_xor(acc6, 16); acc6 += __shfl_xor(acc6, 32);
    acc7 += __shfl_xor(acc7, 8); acc7 += __shfl_xor(acc7, 16); acc7 += __shfl_xor(acc7, 32);

    if (g == 0) {   // lane == h8; s = denom for head h8
        float r = 1.f / s;
        float4 bA = *(const float4*)(b1 + h8 * 8);
        float4 bB = *(const float4*)(b1 + h8 * 8 + 4);
        float v0 = acc0 * r + bA.x, v1 = acc1 * r + bA.y;
        float v2 = acc2 * r + bA.z, v3 = acc3 * r + bA.w;
        float v4 = acc4 * r + bB.x, v5 = acc5 * r + bB.y;
        float v6 = acc6 * r + bB.z, v7 = acc7 * r + bB.w;
        v0 = (v0 > 0.f) ? v0 : (__expf(v0) - 1.f);
        v1 = (v1 > 0.f) ? v1 : (__expf(v1) - 1.f);
        v2 = (v2 > 0.f) ? v2 : (__expf(v2) - 1.f);
        v3 = (v3 > 0.f) ? v3 : (__expf(v3) - 1.f);
        v4 = (v4 > 0.f) ? v4 : (__expf(v4) - 1.f);
        v5 = (v5 > 0.f) ? v5 : (__expf(v5) - 1.f);
        v6 = (v6 > 0.f) ? v6 : (__expf(v6) - 1.f);
        v7 = (v7 > 0.f) ? v7 : (__expf(v7) - 1.f);
        uint4 st;
        st.x = ((unsigned)(unsigned short)f2bf(v0)) | (((unsigned)(unsigned short)f2bf(v1)) << 16);
        st.y = ((unsigned)(unsigned short)f2bf(v2)) | (((unsigned)(unsigned short)f2bf(v3)) << 16);
        st.z = ((unsigned)(unsigned short)f2bf(v4)) | (((unsigned)(unsigned short)f2bf(v5)) << 16);
        st.w = ((unsigned)(unsigned short)f2bf(v6)) | (((unsigned)(unsigned short)f2bf(v7)) << 16);
        *(uint4*)(helu + (size_t)n * 64 + h8 * 8) = st;
    }
}

// -------- GEMM2 (MFMA): h2p = bf16(helu @ W2), rows PADDED to 64 cols --------
__global__ __launch_bounds__(256) void gemm2_mfma(
    const unsigned short* __restrict__ hin, const float* __restrict__ W2,
    const float* __restrict__ att_src2, const float* __restrict__ att_dst2,
    unsigned short* __restrict__ h2p, float* __restrict__ a_src, float* __restrict__ a_dst, int N)
{
    __shared__ short Bl[6 * 64 * 8];
    __shared__ float Cs[4][32 * 48];
    int tid = threadIdx.x;
    for (int f0 = tid; f0 < 384; f0 += 256) {
        int lane = f0 & 63; int fr = f0 >> 6; int s = fr & 1, ct = fr >> 1;
        int kb = s * 32 + ((lane >> 4) << 3);
        int col = ct * 16 + (lane & 15);
        short* dp = &Bl[f0 * 8];
#pragma unroll
        for (int j = 0; j < 8; ++j) dp[j] = (col < 40) ? f2bf(W2[(kb + j) * 40 + col]) : (short)0;
    }
    __syncthreads();

    int lane = tid & 63, w = tid >> 6;
    int row0 = blockIdx.x * 128 + w * 32;
    int ra = min(row0 + (lane & 15), N - 1);
    int rb = min(row0 + 16 + (lane & 15), N - 1);
    const unsigned short* pa = hin + (size_t)ra * 64 + ((lane >> 4) << 3);
    const unsigned short* pb = hin + (size_t)rb * 64 + ((lane >> 4) << 3);

    f32x4 acc[2][3];
#pragma unroll
    for (int i = 0; i < 2; ++i)
#pragma unroll
        for (int j = 0; j < 3; ++j) acc[i][j] = (f32x4){0.f, 0.f, 0.f, 0.f};

#pragma unroll
    for (int s = 0; s < 2; ++s) {
        short8 af = *(const short8*)(pa + s * 32);
        short8 cf = *(const short8*)(pb + s * 32);
#pragma unroll
        for (int ct = 0; ct < 3; ++ct) {
            short8 wf = *(const short8*)&Bl[((ct * 2 + s) * 64 + lane) * 8];
            acc[0][ct] = __builtin_amdgcn_mfma_f32_16x16x32_bf16(af, wf, acc[0][ct], 0, 0, 0);
            acc[1][ct] = __builtin_amdgcn_mfma_f32_16x16x32_bf16(cf, wf, acc[1][ct], 0, 0, 0);
        }
    }

    float* cs = &Cs[w][0];
#pragma unroll
    for (int rt = 0; rt < 2; ++rt)
#pragma unroll
        for (int ct = 0; ct < 3; ++ct)
#pragma unroll
            for (int r = 0; r < 4; ++r) {
                int row = rt * 16 + ((lane >> 4) << 2) + r;
                int col = ct * 16 + (lane & 15);
                cs[row * 48 + col] = acc[rt][ct][r];
            }
    __syncthreads();

    float asv = (lane < 40) ? att_src2[lane] : 0.f;
    float adv = (lane < 40) ? att_dst2[lane] : 0.f;
    for (int r = 0; r < 32; ++r) {
        int row = row0 + r;
        float v = (lane < 48) ? cs[r * 48 + lane] : 0.f;
        float ts = (lane < 40) ? v * asv : 0.f;
        float td = (lane < 40) ? v * adv : 0.f;
        for (int st = 1; st < 64; st <<= 1) { ts += __shfl_xor(ts, st); td += __shfl_xor(td, st); }
        if (row < N) {
            h2p[(size_t)row * 64 + lane] = (unsigned short)f2bf(v);  // padded row
            if (lane == 0) { a_src[row] = ts; a_dst[row] = td; }
        }
    }
}

// ---------------- layer-2 aggregate: merged single pass, octet layout ----------------
__global__ __launch_bounds__(256) void agg2_kernel(
    const unsigned short* __restrict__ h2p, const float* __restrict__ a_src, const float* __restrict__ a_dst,
    const int* __restrict__ off, const int* __restrict__ deg, const int* __restrict__ csr,
    const float* __restrict__ b2, float* __restrict__ out, int N)
{
    int tid = threadIdx.x;
    int n = (blockIdx.x * 256 + tid) >> 6;
    int lane = tid & 63;
    if (n >= N) return;
    int o = off[n], d = deg[n];
    int h8 = lane & 7, g = lane >> 3;

    float adst = a_dst[n];
    float pself = __expf(leaky(a_src[n] + adst));
    float sp = (g == 0) ? pself : 0.f;

    float aself = (g == 0) ? pself : 0.f;
    uint4 dvs = *(const uint4*)(h2p + (size_t)n * 64 + h8 * 8);
    float lo, hi;
    float acc0, acc1, acc2, acc3, acc4, acc5, acc6, acc7;
    unpack2(dvs.x, lo, hi); acc0 = aself * lo; acc1 = aself * hi;
    unpack2(dvs.y, lo, hi); acc2 = aself * lo; acc3 = aself * hi;
    unpack2(dvs.z, lo, hi); acc4 = aself * lo; acc5 = aself * hi;
    unpack2(dvs.w, lo, hi); acc6 = aself * lo; acc7 = aself * hi;

    for (int base = 0; base < d; base += 64) {
        int idx = base + lane;
        int sv = (idx < d) ? csr[o + idx] : 0;
        int lim = min(64, d - base);
        int tmax2 = (((lim + 7) >> 3) + 1) & ~1;
        for (int t = 0; t < tmax2; t += 2) {
            int e0 = t * 8 + g, e1 = e0 + 8;
            int s0 = __shfl(sv, e0), s1 = __shfl(sv, e1);
            float as0 = a_src[s0];
            float as1 = a_src[s1];
            uint4 d0 = *(const uint4*)(h2p + (size_t)s0 * 64 + h8 * 8);
            uint4 d1 = *(const uint4*)(h2p + (size_t)s1 * 64 + h8 * 8);
            float p0 = (e0 < lim) ? __expf(leaky(as0 + adst)) : 0.f;
            float p1 = (e1 < lim) ? __expf(leaky(as1 + adst)) : 0.f;
            sp += p0 + p1;
            unpack2(d0.x, lo, hi); acc0 = fmaf(p0, lo, acc0); acc1 = fmaf(p0, hi, acc1);
            unpack2(d0.y, lo, hi); acc2 = fmaf(p0, lo, acc2); acc3 = fmaf(p0, hi, acc3);
            unpack2(d0.z, lo, hi); acc4 = fmaf(p0, lo, acc4); acc5 = fmaf(p0, hi, acc5);
            unpack2(d0.w, lo, hi); acc6 = fmaf(p0, lo, acc6); acc7 = fmaf(p0, hi, acc7);
            unpack2(d1.x, lo, hi); acc0 = fmaf(p1, lo, acc0); acc1 = fmaf(p1, hi, acc1);
            unpack2(d1.y, lo, hi); acc2 = fmaf(p1, lo, acc2); acc3 = fmaf(p1, hi, acc3);
            unpack2(d1.z, lo, hi); acc4 = fmaf(p1, lo, acc4); acc5 = fmaf(p1, hi, acc5);
            unpack2(d1.w, lo, hi); acc6 = fmaf(p1, lo, acc6); acc7 = fmaf(p1, hi, acc7);
        }
    }
    // reduce over edge groups (g bits); each edge counted once since only g varies
    sp += __shfl_xor(sp, 8); sp += __shfl_xor(sp, 16); sp += __shfl_xor(sp, 32);
    acc0 += __shfl_xor(acc0, 8); acc0 += __shfl_xor(acc0, 16); acc0 += __shfl_xor(acc0, 32);
    acc1 += __shfl_xor(acc1, 8); acc1 += __shfl_xor(acc1, 16); acc1 += __shfl_xor(acc1, 32);
    acc2 += __shfl_xor(acc2, 8); acc2 += __shfl_xor(acc2, 16); acc2 += __shfl_xor(acc2, 32);
    acc3 += __shfl_xor(acc3, 8); acc3 += __shfl_xor(acc3, 16); acc3 += __shfl_xor(acc3, 32);
    acc4 += __shfl_xor(acc4, 8); acc4 += __shfl_xor(acc4, 16); acc4 += __shfl_xor(acc4, 32);
    acc5 += __shfl_xor(acc5, 8); acc5 += __shfl_xor(acc5, 16); acc5 += __shfl_xor(acc5, 32);
    acc6 += __shfl_xor(acc6, 8); acc6 += __shfl_xor(acc6, 16); acc6 += __shfl_xor(acc6, 32);
    acc7 += __shfl_xor(acc7, 8); acc7 += __shfl_xor(acc7, 16); acc7 += __shfl_xor(acc7, 32);

    if (g == 0) {   // lanes 0..7 hold cols 8*h8..8*h8+7; only h8<5 valid (40 cols)
        float r = 1.f / sp;
        float v0 = -INFINITY, v1 = -INFINITY, v2 = -INFINITY, v3 = -INFINITY;
        float v4 = -INFINITY, v5 = -INFINITY, v6 = -INFINITY, v7 = -INFINITY;
        if (h8 < 5) {
            float4 bA = *(const float4*)(b2 + h8 * 8);
            float4 bB = *(const float4*)(b2 + h8 * 8 + 4);
            v0 = acc0 * r + bA.x; v1 = acc1 * r + bA.y;
            v2 = acc2 * r + bA.z; v3 = acc3 * r + bA.w;
            v4 = acc4 * r + bB.x; v5 = acc5 * r + bB.y;
            v6 = acc6 * r + bB.z; v7 = acc7 * r + bB.w;
        }
        float mx = fmaxf(fmaxf(fmaxf(v0, v1), fmaxf(v2, v3)), fmaxf(fmaxf(v4, v5), fmaxf(v6, v7)));
        mx = fmaxf(mx, __shfl_xor(mx, 1));
        mx = fmaxf(mx, __shfl_xor(mx, 2));
        mx = fmaxf(mx, __shfl_xor(mx, 4));
        float se = 0.f;
        if (h8 < 5)
            se = __expf(v0 - mx) + __expf(v1 - mx) + __expf(v2 - mx) + __expf(v3 - mx)
               + __expf(v4 - mx) + __expf(v5 - mx) + __expf(v6 - mx) + __expf(v7 - mx);
        se += __shfl_xor(se, 1); se += __shfl_xor(se, 2); se += __shfl_xor(se, 4);
        if (h8 < 5) {
            float ls = mx + logf(se);
            float* op = out + (size_t)n * 40 + h8 * 8;
            *(float4*)op = make_float4(v0 - ls, v1 - ls, v2 - ls, v3 - ls);
            *(float4*)(op + 4) = make_float4(v4 - ls, v5 - ls, v6 - ls, v7 - ls);
        }
    }
}

extern "C" void kernel_launch(void* const* d_in, const int* in_sizes, int n_in,
                              void* d_out, int out_size, void* d_ws, size_t ws_size,
                              hipStream_t stream) {
    const float* x        = (const float*)d_in[0];
    const int*   ei       = (const int*)d_in[1];
    const float* W1       = (const float*)d_in[2];
    const float* att_src1 = (const float*)d_in[3];
    const float* att_dst1 = (const float*)d_in[4];
    const float* b1       = (const float*)d_in[5];
    const float* W2       = (const float*)d_in[6];
    const float* att_src2 = (const float*)d_in[7];
    const float* att_dst2 = (const float*)d_in[8];
    const float* b2       = (const float*)d_in[9];
    float* out = (float*)d_out;

    int N = in_sizes[0] / 128;
    int E = in_sizes[1] / 2;
    const int* src = ei;
    const int* dst = ei + E;
    int nbuck = (N + 127) >> 7;

    char* w = (char*)d_ws;
    auto alloc = [&](size_t bytes) { void* p = (void*)w; w += (bytes + 255) & ~(size_t)255; return p; };
    unsigned short* h1   = (unsigned short*)alloc((size_t)N * 64 * 2);
    unsigned short* helu = (unsigned short*)alloc((size_t)N * 64 * 2);
    float* as1  = (float*)alloc((size_t)N * 8 * 4);
    float* ad1  = (float*)alloc((size_t)N * 8 * 4);
    int*   degv = (int*)alloc((size_t)N * 4);
    int*   offv = (int*)alloc((size_t)(N + 1) * 4);
    int*   csr  = (int*)alloc((size_t)E * 4);
    int*   histG  = (int*)alloc((size_t)nbuck * GCHUNK * 4);
    int*   startG = (int*)alloc((size_t)nbuck * GCHUNK * 4);
    int*   total  = (int*)alloc((size_t)nbuck * 4);
    int*   bbase  = (int*)alloc((size_t)(nbuck + 1) * 4);
    int*   pairbuf = (int*)alloc((size_t)E * 4);
    unsigned short* h2p = h1;   // reuse: h1 dead after agg1
    float* as2 = as1;
    float* ad2 = ad1;

    hipMemsetAsync(total, 0, (size_t)nbuck * 4, stream);
    hist_kernel<<<GCHUNK, 256, 0, stream>>>(dst, E, nbuck, histG, total);
    bscan_kernel<<<1, 1024, 0, stream>>>(total, bbase, nbuck);
    bstart_kernel<<<nbuck, 256, 0, stream>>>(histG, bbase, startG, nbuck);
    bucket_scatter<<<GCHUNK, 256, 0, stream>>>(src, dst, E, nbuck, startG, pairbuf);
    bucket_place<<<nbuck, 256, 0, stream>>>(pairbuf, bbase, nbuck, N, degv, offv, csr);

    int gb = (N + 127) / 128;
    gemm1_mfma<<<gb, 256, 0, stream>>>(x, W1, att_src1, att_dst1, h1, as1, ad1, N);
    agg1_kernel<<<(N + 3) / 4, 256, 0, stream>>>(h1, as1, ad1, offv, degv, csr, b1, helu, N);
    gemm2_mfma<<<gb, 256, 0, stream>>>(helu, W2, att_src2, att_dst2, h2p, as2, ad2, N);
    agg2_kernel<<<(N + 3) / 4, 256, 0, stream>>>(h2p, as2, ad2, offv, degv, csr, b2, out, N);
}

// Round 8
// 291.927 us; speedup vs baseline: 1.1828x; 1.1219x over previous
//
#include <hip/hip_runtime.h>
#include <math.h>

#define NEG_SLOPE 0.2f

typedef __attribute__((ext_vector_type(8))) short short8;
typedef __attribute__((ext_vector_type(4))) float f32x4;

__device__ __forceinline__ float leaky(float x) { return x > 0.f ? x : NEG_SLOPE * x; }

// fp32 -> bf16 (RNE)
__device__ __forceinline__ short f2bf(float f) {
    union { float f; unsigned u; } v; v.f = f;
    unsigned r = v.u + 0x7fffu + ((v.u >> 16) & 1u);
    return (short)(r >> 16);
}
__device__ __forceinline__ float bf2f(unsigned short s) {
    union { unsigned u; float f; } v; v.u = ((unsigned)s) << 16;
    return v.f;
}
// unpack a dword holding two bf16 (lo = even col, hi = odd col)
__device__ __forceinline__ void unpack2(unsigned v, float& lo, float& hi) {
    union { unsigned u; float f; } a, b;
    a.u = v << 16; b.u = v & 0xffff0000u;
    lo = a.f; hi = b.f;
}

// ================= CSR build: workgroup-exclusive counting sort =================
#define GCHUNK 256
#define NB_MAX 1024   // supports N <= 131072

__global__ __launch_bounds__(256) void hist_kernel(const int* __restrict__ dst, int E, int nbuck,
                                                   int* __restrict__ histG, int* __restrict__ total) {
    __shared__ int lh[NB_MAX];
    int g = blockIdx.x, t = threadIdx.x;
    for (int i = t; i < nbuck; i += 256) lh[i] = 0;
    __syncthreads();
    int ce = (E + GCHUNK - 1) / GCHUNK;
    int e0 = g * ce, e1 = min(e0 + ce, E);
    for (int e = e0 + t; e < e1; e += 256)
        atomicAdd(&lh[dst[e] >> 7], 1);
    __syncthreads();
    for (int i = t; i < nbuck; i += 256) {
        histG[i * GCHUNK + g] = lh[i];
        if (lh[i]) atomicAdd(&total[i], lh[i]);
    }
}

__global__ __launch_bounds__(1024) void bscan_kernel(const int* __restrict__ total,
                                                     int* __restrict__ bbase, int nbuck) {
    __shared__ int sh[1024];
    int t = threadIdx.x;
    int v = (t < nbuck) ? total[t] : 0;
    sh[t] = v; __syncthreads();
    for (int s = 1; s < 1024; s <<= 1) {
        int add = (t >= s) ? sh[t - s] : 0;
        __syncthreads();
        sh[t] += add;
        __syncthreads();
    }
    if (t < nbuck) bbase[t] = sh[t] - v;
    if (t == nbuck - 1) bbase[nbuck] = sh[t];
}

__global__ __launch_bounds__(256) void bstart_kernel(const int* __restrict__ histG,
                                                     const int* __restrict__ bbase,
                                                     int* __restrict__ startG, int nbuck) {
    __shared__ int sh[256];
    int b = blockIdx.x, t = threadIdx.x;
    int v = histG[b * GCHUNK + t];
    sh[t] = v; __syncthreads();
    for (int s = 1; s < 256; s <<= 1) {
        int add = (t >= s) ? sh[t - s] : 0;
        __syncthreads();
        sh[t] += add;
        __syncthreads();
    }
    startG[b * GCHUNK + t] = bbase[b] + sh[t] - v;
}

__global__ __launch_bounds__(256) void bucket_scatter(const int* __restrict__ src,
                                                      const int* __restrict__ dst, int E, int nbuck,
                                                      const int* __restrict__ startG,
                                                      int* __restrict__ pairbuf) {
    __shared__ int cur[NB_MAX];
    int g = blockIdx.x, t = threadIdx.x;
    for (int i = t; i < nbuck; i += 256) cur[i] = startG[i * GCHUNK + g];
    __syncthreads();
    int ce = (E + GCHUNK - 1) / GCHUNK;
    int e0 = g * ce, e1 = min(e0 + ce, E);
    for (int e = e0 + t; e < e1; e += 256) {
        int d = dst[e], b = d >> 7;
        int pos = atomicAdd(&cur[b], 1);
        pairbuf[pos] = (src[e] << 7) | (d & 127);
    }
}

__global__ __launch_bounds__(256) void bucket_place(const int* __restrict__ pairbuf,
                                                    const int* __restrict__ bbase, int nbuck, int N,
                                                    int* __restrict__ deg, int* __restrict__ off,
                                                    int* __restrict__ csr) {
    __shared__ int stash[4096];
    __shared__ int ldeg[128], lcur[128], sh[128];
    int b = blockIdx.x, t = threadIdx.x;
    int p0 = bbase[b], p1 = bbase[b + 1];
    int cnt = p1 - p0;
    int node0 = b << 7;
    for (int i = t; i < 128; i += 256) ldeg[i] = 0;
    __syncthreads();
    for (int i = t; i < cnt; i += 256) {
        int pr = pairbuf[p0 + i];
        if (i < 4096) stash[i] = pr;
        atomicAdd(&ldeg[pr & 127], 1);
    }
    __syncthreads();
    if (t < 128) sh[t] = ldeg[t];
    __syncthreads();
    for (int s = 1; s < 128; s <<= 1) {
        int add = (t >= s && t < 128) ? sh[t - s] : 0;
        __syncthreads();
        if (t < 128) sh[t] += add;
        __syncthreads();
    }
    if (t < 128) {
        int excl = sh[t] - ldeg[t];
        int n = node0 + t;
        if (n < N) { deg[n] = ldeg[t]; off[n] = p0 + excl; }
        lcur[t] = p0 + excl;
    }
    __syncthreads();
    for (int i = t; i < cnt; i += 256) {
        int pr = (i < 4096) ? stash[i] : pairbuf[p0 + i];
        int pos = atomicAdd(&lcur[pr & 127], 1);
        csr[pos] = ((unsigned)pr) >> 7;
    }
}

// ---------------- GEMM1 (MFMA): h1 = bf16(x @ W1), dots in fp32 ----------------
__global__ __launch_bounds__(256) void gemm1_mfma(
    const float* __restrict__ x, const float* __restrict__ W1,
    const float* __restrict__ att_src, const float* __restrict__ att_dst,
    unsigned short* __restrict__ h1, float* __restrict__ a_src, float* __restrict__ a_dst, int N)
{
    __shared__ short Bl[16 * 64 * 8];   // 16 B-frags (ct,s), 16 KB
    __shared__ float Cs[4][32 * 64];    // fp32 C stage, 32 KB
    int tid = threadIdx.x;
    for (int f0 = tid; f0 < 1024; f0 += 256) {
        int lane = f0 & 63, s = (f0 >> 6) & 3, ct = f0 >> 8;
        int kb = s * 32 + ((lane >> 4) << 3);
        int col = ct * 16 + (lane & 15);
        short* dp = &Bl[f0 * 8];
#pragma unroll
        for (int j = 0; j < 8; ++j) dp[j] = f2bf(W1[(kb + j) * 64 + col]);
    }
    __syncthreads();

    int lane = tid & 63, w = tid >> 6;
    int row0 = blockIdx.x * 128 + w * 32;
    int ra = min(row0 + (lane & 15), N - 1);
    int rb = min(row0 + 16 + (lane & 15), N - 1);
    const float* pa = x + (size_t)ra * 128 + ((lane >> 4) << 3);
    const float* pb = x + (size_t)rb * 128 + ((lane >> 4) << 3);

    f32x4 acc[2][4];
#pragma unroll
    for (int i = 0; i < 2; ++i)
#pragma unroll
        for (int j = 0; j < 4; ++j) acc[i][j] = (f32x4){0.f, 0.f, 0.f, 0.f};

#pragma unroll
    for (int s = 0; s < 4; ++s) {
        float4 a0 = *(const float4*)(pa + s * 32);
        float4 a1 = *(const float4*)(pa + s * 32 + 4);
        float4 c0 = *(const float4*)(pb + s * 32);
        float4 c1 = *(const float4*)(pb + s * 32 + 4);
        short8 af, cf;
        af[0] = f2bf(a0.x); af[1] = f2bf(a0.y); af[2] = f2bf(a0.z); af[3] = f2bf(a0.w);
        af[4] = f2bf(a1.x); af[5] = f2bf(a1.y); af[6] = f2bf(a1.z); af[7] = f2bf(a1.w);
        cf[0] = f2bf(c0.x); cf[1] = f2bf(c0.y); cf[2] = f2bf(c0.z); cf[3] = f2bf(c0.w);
        cf[4] = f2bf(c1.x); cf[5] = f2bf(c1.y); cf[6] = f2bf(c1.z); cf[7] = f2bf(c1.w);
#pragma unroll
        for (int ct = 0; ct < 4; ++ct) {
            short8 wf = *(const short8*)&Bl[((ct * 4 + s) * 64 + lane) * 8];
            acc[0][ct] = __builtin_amdgcn_mfma_f32_16x16x32_bf16(af, wf, acc[0][ct], 0, 0, 0);
            acc[1][ct] = __builtin_amdgcn_mfma_f32_16x16x32_bf16(cf, wf, acc[1][ct], 0, 0, 0);
        }
    }

    float* cs = &Cs[w][0];
#pragma unroll
    for (int rt = 0; rt < 2; ++rt)
#pragma unroll
        for (int ct = 0; ct < 4; ++ct)
#pragma unroll
            for (int r = 0; r < 4; ++r) {
                int row = rt * 16 + ((lane >> 4) << 2) + r;
                int col = ct * 16 + (lane & 15);
                cs[row * 64 + col] = acc[rt][ct][r];
            }
    __syncthreads();

    float asv = att_src[lane], adv = att_dst[lane];
    for (int r = 0; r < 32; ++r) {
        int row = row0 + r;
        float v = cs[r * 64 + lane];
        float ts = v * asv, td = v * adv;
        ts += __shfl_xor(ts, 1); ts += __shfl_xor(ts, 2); ts += __shfl_xor(ts, 4);
        td += __shfl_xor(td, 1); td += __shfl_xor(td, 2); td += __shfl_xor(td, 4);
        if (row < N) {
            h1[(size_t)row * 64 + lane] = (unsigned short)f2bf(v);
            if ((lane & 7) == 0) {
                a_src[row * 8 + (lane >> 3)] = ts;
                a_dst[row * 8 + (lane >> 3)] = td;
            }
        }
    }
}

// ---------------- layer-1 aggregate: 2 nodes/wave (32 lanes each), octet cols ----------------
// half-lane l32 = (g = l32>>3 in [0,4) edge-group, h8 = l32&7 col-octet == head).
// Per-node fixed cost (preamble/reduction/epilogue) is shared by 2 nodes; 4-slot
// granularity + single-iter tail cuts padding (deg 17: 20 slots vs 32 before).
__global__ __launch_bounds__(256) void agg1_kernel(
    const unsigned short* __restrict__ h1, const float* __restrict__ a_src, const float* __restrict__ a_dst,
    const int* __restrict__ off, const int* __restrict__ deg, const int* __restrict__ csr,
    const float* __restrict__ b1, unsigned short* __restrict__ helu, int N)
{
    int tid = threadIdx.x;
    int n = (blockIdx.x * 256 + tid) >> 5;   // 32 lanes per node
    int lane = tid & 63;
    int l32 = lane & 31;
    int hb = lane & 32;                      // half base for shfl indices
    if (n >= N) return;
    int o = off[n], d = deg[n];
    int h8 = l32 & 7, g = l32 >> 3;

    float adst = a_dst[n * 8 + h8];
    float pself = __expf(leaky(a_src[n * 8 + h8] + adst));
    float s = (g == 0) ? pself : 0.f;

    float lo, hi;
    float acc0 = 0.f, acc1 = 0.f, acc2 = 0.f, acc3 = 0.f;
    float acc4 = 0.f, acc5 = 0.f, acc6 = 0.f, acc7 = 0.f;
    if (g == 0) {   // self loop: lane's own pself IS head h8's value here
        uint4 dvs = *(const uint4*)(h1 + (size_t)n * 64 + h8 * 8);
        unpack2(dvs.x, lo, hi); acc0 = pself * lo; acc1 = pself * hi;
        unpack2(dvs.y, lo, hi); acc2 = pself * lo; acc3 = pself * hi;
        unpack2(dvs.z, lo, hi); acc4 = pself * lo; acc5 = pself * hi;
        unpack2(dvs.w, lo, hi); acc6 = pself * lo; acc7 = pself * hi;
    }

    for (int base = 0; base < d; base += 32) {
        int idx = base + l32;
        int sv = (idx < d) ? csr[o + idx] : 0;
        int lim = min(32, d - base);
        int tm = (lim + 3) >> 2;     // number of 4-slot groups
        int t = 0;
        for (; t + 1 < tm; t += 2) {
            int e0 = t * 4 + g, e1 = e0 + 4;
            int s0 = __shfl(sv, hb | e0), s1 = __shfl(sv, hb | e1);
            float as0 = a_src[s0 * 8 + h8];
            float as1 = a_src[s1 * 8 + h8];
            uint4 d0 = *(const uint4*)(h1 + (size_t)s0 * 64 + h8 * 8);
            uint4 d1 = *(const uint4*)(h1 + (size_t)s1 * 64 + h8 * 8);
            float p0 = (e0 < lim) ? __expf(leaky(as0 + adst)) : 0.f;
            float p1 = (e1 < lim) ? __expf(leaky(as1 + adst)) : 0.f;
            s += p0 + p1;
            unpack2(d0.x, lo, hi); acc0 = fmaf(p0, lo, acc0); acc1 = fmaf(p0, hi, acc1);
            unpack2(d0.y, lo, hi); acc2 = fmaf(p0, lo, acc2); acc3 = fmaf(p0, hi, acc3);
            unpack2(d0.z, lo, hi); acc4 = fmaf(p0, lo, acc4); acc5 = fmaf(p0, hi, acc5);
            unpack2(d0.w, lo, hi); acc6 = fmaf(p0, lo, acc6); acc7 = fmaf(p0, hi, acc7);
            unpack2(d1.x, lo, hi); acc0 = fmaf(p1, lo, acc0); acc1 = fmaf(p1, hi, acc1);
            unpack2(d1.y, lo, hi); acc2 = fmaf(p1, lo, acc2); acc3 = fmaf(p1, hi, acc3);
            unpack2(d1.z, lo, hi); acc4 = fmaf(p1, lo, acc4); acc5 = fmaf(p1, hi, acc5);
            unpack2(d1.w, lo, hi); acc6 = fmaf(p1, lo, acc6); acc7 = fmaf(p1, hi, acc7);
        }
        if (t < tm) {   // single tail group
            int e0 = t * 4 + g;
            int s0 = __shfl(sv, hb | e0);
            float as0 = a_src[s0 * 8 + h8];
            uint4 d0 = *(const uint4*)(h1 + (size_t)s0 * 64 + h8 * 8);
            float p0 = (e0 < lim) ? __expf(leaky(as0 + adst)) : 0.f;
            s += p0;
            unpack2(d0.x, lo, hi); acc0 = fmaf(p0, lo, acc0); acc1 = fmaf(p0, hi, acc1);
            unpack2(d0.y, lo, hi); acc2 = fmaf(p0, lo, acc2); acc3 = fmaf(p0, hi, acc3);
            unpack2(d0.z, lo, hi); acc4 = fmaf(p0, lo, acc4); acc5 = fmaf(p0, hi, acc5);
            unpack2(d0.w, lo, hi); acc6 = fmaf(p0, lo, acc6); acc7 = fmaf(p0, hi, acc7);
        }
    }
    // reduce over the 4 edge groups (g bits 3,4 of l32) — stays within the half
    s += __shfl_xor(s, 8); s += __shfl_xor(s, 16);
    acc0 += __shfl_xor(acc0, 8); acc0 += __shfl_xor(acc0, 16);
    acc1 += __shfl_xor(acc1, 8); acc1 += __shfl_xor(acc1, 16);
    acc2 += __shfl_xor(acc2, 8); acc2 += __shfl_xor(acc2, 16);
    acc3 += __shfl_xor(acc3, 8); acc3 += __shfl_xor(acc3, 16);
    acc4 += __shfl_xor(acc4, 8); acc4 += __shfl_xor(acc4, 16);
    acc5 += __shfl_xor(acc5, 8); acc5 += __shfl_xor(acc5, 16);
    acc6 += __shfl_xor(acc6, 8); acc6 += __shfl_xor(acc6, 16);
    acc7 += __shfl_xor(acc7, 8); acc7 += __shfl_xor(acc7, 16);

    if (g == 0) {   // l32 == h8; s = denom for head h8
        float r = 1.f / s;
        float4 bA = *(const float4*)(b1 + h8 * 8);
        float4 bB = *(const float4*)(b1 + h8 * 8 + 4);
        float v0 = acc0 * r + bA.x, v1 = acc1 * r + bA.y;
        float v2 = acc2 * r + bA.z, v3 = acc3 * r + bA.w;
        float v4 = acc4 * r + bB.x, v5 = acc5 * r + bB.y;
        float v6 = acc6 * r + bB.z, v7 = acc7 * r + bB.w;
        v0 = (v0 > 0.f) ? v0 : (__expf(v0) - 1.f);
        v1 = (v1 > 0.f) ? v1 : (__expf(v1) - 1.f);
        v2 = (v2 > 0.f) ? v2 : (__expf(v2) - 1.f);
        v3 = (v3 > 0.f) ? v3 : (__expf(v3) - 1.f);
        v4 = (v4 > 0.f) ? v4 : (__expf(v4) - 1.f);
        v5 = (v5 > 0.f) ? v5 : (__expf(v5) - 1.f);
        v6 = (v6 > 0.f) ? v6 : (__expf(v6) - 1.f);
        v7 = (v7 > 0.f) ? v7 : (__expf(v7) - 1.f);
        uint4 st;
        st.x = ((unsigned)(unsigned short)f2bf(v0)) | (((unsigned)(unsigned short)f2bf(v1)) << 16);
        st.y = ((unsigned)(unsigned short)f2bf(v2)) | (((unsigned)(unsigned short)f2bf(v3)) << 16);
        st.z = ((unsigned)(unsigned short)f2bf(v4)) | (((unsigned)(unsigned short)f2bf(v5)) << 16);
        st.w = ((unsigned)(unsigned short)f2bf(v6)) | (((unsigned)(unsigned short)f2bf(v7)) << 16);
        *(uint4*)(helu + (size_t)n * 64 + h8 * 8) = st;
    }
}

// -------- GEMM2 (MFMA): h2p = bf16(helu @ W2), rows PADDED to 64 cols --------
__global__ __launch_bounds__(256) void gemm2_mfma(
    const unsigned short* __restrict__ hin, const float* __restrict__ W2,
    const float* __restrict__ att_src2, const float* __restrict__ att_dst2,
    unsigned short* __restrict__ h2p, float* __restrict__ a_src, float* __restrict__ a_dst, int N)
{
    __shared__ short Bl[6 * 64 * 8];
    __shared__ float Cs[4][32 * 48];
    int tid = threadIdx.x;
    for (int f0 = tid; f0 < 384; f0 += 256) {
        int lane = f0 & 63; int fr = f0 >> 6; int s = fr & 1, ct = fr >> 1;
        int kb = s * 32 + ((lane >> 4) << 3);
        int col = ct * 16 + (lane & 15);
        short* dp = &Bl[f0 * 8];
#pragma unroll
        for (int j = 0; j < 8; ++j) dp[j] = (col < 40) ? f2bf(W2[(kb + j) * 40 + col]) : (short)0;
    }
    __syncthreads();

    int lane = tid & 63, w = tid >> 6;
    int row0 = blockIdx.x * 128 + w * 32;
    int ra = min(row0 + (lane & 15), N - 1);
    int rb = min(row0 + 16 + (lane & 15), N - 1);
    const unsigned short* pa = hin + (size_t)ra * 64 + ((lane >> 4) << 3);
    const unsigned short* pb = hin + (size_t)rb * 64 + ((lane >> 4) << 3);

    f32x4 acc[2][3];
#pragma unroll
    for (int i = 0; i < 2; ++i)
#pragma unroll
        for (int j = 0; j < 3; ++j) acc[i][j] = (f32x4){0.f, 0.f, 0.f, 0.f};

#pragma unroll
    for (int s = 0; s < 2; ++s) {
        short8 af = *(const short8*)(pa + s * 32);
        short8 cf = *(const short8*)(pb + s * 32);
#pragma unroll
        for (int ct = 0; ct < 3; ++ct) {
            short8 wf = *(const short8*)&Bl[((ct * 2 + s) * 64 + lane) * 8];
            acc[0][ct] = __builtin_amdgcn_mfma_f32_16x16x32_bf16(af, wf, acc[0][ct], 0, 0, 0);
            acc[1][ct] = __builtin_amdgcn_mfma_f32_16x16x32_bf16(cf, wf, acc[1][ct], 0, 0, 0);
        }
    }

    float* cs = &Cs[w][0];
#pragma unroll
    for (int rt = 0; rt < 2; ++rt)
#pragma unroll
        for (int ct = 0; ct < 3; ++ct)
#pragma unroll
            for (int r = 0; r < 4; ++r) {
                int row = rt * 16 + ((lane >> 4) << 2) + r;
                int col = ct * 16 + (lane & 15);
                cs[row * 48 + col] = acc[rt][ct][r];
            }
    __syncthreads();

    float asv = (lane < 40) ? att_src2[lane] : 0.f;
    float adv = (lane < 40) ? att_dst2[lane] : 0.f;
    for (int r = 0; r < 32; ++r) {
        int row = row0 + r;
        float v = (lane < 48) ? cs[r * 48 + lane] : 0.f;
        float ts = (lane < 40) ? v * asv : 0.f;
        float td = (lane < 40) ? v * adv : 0.f;
        for (int st = 1; st < 64; st <<= 1) { ts += __shfl_xor(ts, st); td += __shfl_xor(td, st); }
        if (row < N) {
            h2p[(size_t)row * 64 + lane] = (unsigned short)f2bf(v);  // padded row
            if (lane == 0) { a_src[row] = ts; a_dst[row] = td; }
        }
    }
}

// ---------------- layer-2 aggregate: 2 nodes/wave, octet cols, + log_softmax ----------------
__global__ __launch_bounds__(256) void agg2_kernel(
    const unsigned short* __restrict__ h2p, const float* __restrict__ a_src, const float* __restrict__ a_dst,
    const int* __restrict__ off, const int* __restrict__ deg, const int* __restrict__ csr,
    const float* __restrict__ b2, float* __restrict__ out, int N)
{
    int tid = threadIdx.x;
    int n = (blockIdx.x * 256 + tid) >> 5;
    int lane = tid & 63;
    int l32 = lane & 31;
    int hb = lane & 32;
    if (n >= N) return;
    int o = off[n], d = deg[n];
    int h8 = l32 & 7, g = l32 >> 3;

    float adst = a_dst[n];
    float pself = __expf(leaky(a_src[n] + adst));
    float sp = (g == 0) ? pself : 0.f;

    float lo, hi;
    float acc0 = 0.f, acc1 = 0.f, acc2 = 0.f, acc3 = 0.f;
    float acc4 = 0.f, acc5 = 0.f, acc6 = 0.f, acc7 = 0.f;
    if (g == 0) {
        uint4 dvs = *(const uint4*)(h2p + (size_t)n * 64 + h8 * 8);
        unpack2(dvs.x, lo, hi); acc0 = pself * lo; acc1 = pself * hi;
        unpack2(dvs.y, lo, hi); acc2 = pself * lo; acc3 = pself * hi;
        unpack2(dvs.z, lo, hi); acc4 = pself * lo; acc5 = pself * hi;
        unpack2(dvs.w, lo, hi); acc6 = pself * lo; acc7 = pself * hi;
    }

    for (int base = 0; base < d; base += 32) {
        int idx = base + l32;
        int sv = (idx < d) ? csr[o + idx] : 0;
        int lim = min(32, d - base);
        int tm = (lim + 3) >> 2;
        int t = 0;
        for (; t + 1 < tm; t += 2) {
            int e0 = t * 4 + g, e1 = e0 + 4;
            int s0 = __shfl(sv, hb | e0), s1 = __shfl(sv, hb | e1);
            float as0 = a_src[s0];
            float as1 = a_src[s1];
            uint4 d0 = *(const uint4*)(h2p + (size_t)s0 * 64 + h8 * 8);
            uint4 d1 = *(const uint4*)(h2p + (size_t)s1 * 64 + h8 * 8);
            float p0 = (e0 < lim) ? __expf(leaky(as0 + adst)) : 0.f;
            float p1 = (e1 < lim) ? __expf(leaky(as1 + adst)) : 0.f;
            sp += p0 + p1;
            unpack2(d0.x, lo, hi); acc0 = fmaf(p0, lo, acc0); acc1 = fmaf(p0, hi, acc1);
            unpack2(d0.y, lo, hi); acc2 = fmaf(p0, lo, acc2); acc3 = fmaf(p0, hi, acc3);
            unpack2(d0.z, lo, hi); acc4 = fmaf(p0, lo, acc4); acc5 = fmaf(p0, hi, acc5);
            unpack2(d0.w, lo, hi); acc6 = fmaf(p0, lo, acc6); acc7 = fmaf(p0, hi, acc7);
            unpack2(d1.x, lo, hi); acc0 = fmaf(p1, lo, acc0); acc1 = fmaf(p1, hi, acc1);
            unpack2(d1.y, lo, hi); acc2 = fmaf(p1, lo, acc2); acc3 = fmaf(p1, hi, acc3);
            unpack2(d1.z, lo, hi); acc4 = fmaf(p1, lo, acc4); acc5 = fmaf(p1, hi, acc5);
            unpack2(d1.w, lo, hi); acc6 = fmaf(p1, lo, acc6); acc7 = fmaf(p1, hi, acc7);
        }
        if (t < tm) {
            int e0 = t * 4 + g;
            int s0 = __shfl(sv, hb | e0);
            float as0 = a_src[s0];
            uint4 d0 = *(const uint4*)(h2p + (size_t)s0 * 64 + h8 * 8);
            float p0 = (e0 < lim) ? __expf(leaky(as0 + adst)) : 0.f;
            sp += p0;
            unpack2(d0.x, lo, hi); acc0 = fmaf(p0, lo, acc0); acc1 = fmaf(p0, hi, acc1);
            unpack2(d0.y, lo, hi); acc2 = fmaf(p0, lo, acc2); acc3 = fmaf(p0, hi, acc3);
            unpack2(d0.z, lo, hi); acc4 = fmaf(p0, lo, acc4); acc5 = fmaf(p0, hi, acc5);
            unpack2(d0.w, lo, hi); acc6 = fmaf(p0, lo, acc6); acc7 = fmaf(p0, hi, acc7);
        }
    }
    sp += __shfl_xor(sp, 8); sp += __shfl_xor(sp, 16);
    acc0 += __shfl_xor(acc0, 8); acc0 += __shfl_xor(acc0, 16);
    acc1 += __shfl_xor(acc1, 8); acc1 += __shfl_xor(acc1, 16);
    acc2 += __shfl_xor(acc2, 8); acc2 += __shfl_xor(acc2, 16);
    acc3 += __shfl_xor(acc3, 8); acc3 += __shfl_xor(acc3, 16);
    acc4 += __shfl_xor(acc4, 8); acc4 += __shfl_xor(acc4, 16);
    acc5 += __shfl_xor(acc5, 8); acc5 += __shfl_xor(acc5, 16);
    acc6 += __shfl_xor(acc6, 8); acc6 += __shfl_xor(acc6, 16);
    acc7 += __shfl_xor(acc7, 8); acc7 += __shfl_xor(acc7, 16);

    if (g == 0) {   // 8 lanes per half hold cols 8*h8..8*h8+7; h8<5 valid (40 cols)
        float r = 1.f / sp;
        float v0 = -INFINITY, v1 = -INFINITY, v2 = -INFINITY, v3 = -INFINITY;
        float v4 = -INFINITY, v5 = -INFINITY, v6 = -INFINITY, v7 = -INFINITY;
        if (h8 < 5) {
            float4 bA = *(const float4*)(b2 + h8 * 8);
            float4 bB = *(const float4*)(b2 + h8 * 8 + 4);
            v0 = acc0 * r + bA.x; v1 = acc1 * r + bA.y;
            v2 = acc2 * r + bA.z; v3 = acc3 * r + bA.w;
            v4 = acc4 * r + bB.x; v5 = acc5 * r + bB.y;
            v6 = acc6 * r + bB.z; v7 = acc7 * r + bB.w;
        }
        float mx = fmaxf(fmaxf(fmaxf(v0, v1), fmaxf(v2, v3)), fmaxf(fmaxf(v4, v5), fmaxf(v6, v7)));
        mx = fmaxf(mx, __shfl_xor(mx, 1));
        mx = fmaxf(mx, __shfl_xor(mx, 2));
        mx = fmaxf(mx, __shfl_xor(mx, 4));
        float se = 0.f;
        if (h8 < 5)
            se = __expf(v0 - mx) + __expf(v1 - mx) + __expf(v2 - mx) + __expf(v3 - mx)
               + __expf(v4 - mx) + __expf(v5 - mx) + __expf(v6 - mx) + __expf(v7 - mx);
        se += __shfl_xor(se, 1); se += __shfl_xor(se, 2); se += __shfl_xor(se, 4);
        if (h8 < 5) {
            float ls = mx + logf(se);
            float* op = out + (size_t)n * 40 + h8 * 8;
            *(float4*)op = make_float4(v0 - ls, v1 - ls, v2 - ls, v3 - ls);
            *(float4*)(op + 4) = make_float4(v4 - ls, v5 - ls, v6 - ls, v7 - ls);
        }
    }
}

extern "C" void kernel_launch(void* const* d_in, const int* in_sizes, int n_in,
                              void* d_out, int out_size, void* d_ws, size_t ws_size,
                              hipStream_t stream) {
    const float* x        = (const float*)d_in[0];
    const int*   ei       = (const int*)d_in[1];
    const float* W1       = (const float*)d_in[2];
    const float* att_src1 = (const float*)d_in[3];
    const float* att_dst1 = (const float*)d_in[4];
    const float* b1       = (const float*)d_in[5];
    const float* W2       = (const float*)d_in[6];
    const float* att_src2 = (const float*)d_in[7];
    const float* att_dst2 = (const float*)d_in[8];
    const float* b2       = (const float*)d_in[9];
    float* out = (float*)d_out;

    int N = in_sizes[0] / 128;
    int E = in_sizes[1] / 2;
    const int* src = ei;
    const int* dst = ei + E;
    int nbuck = (N + 127) >> 7;

    char* w = (char*)d_ws;
    auto alloc = [&](size_t bytes) { void* p = (void*)w; w += (bytes + 255) & ~(size_t)255; return p; };
    unsigned short* h1   = (unsigned short*)alloc((size_t)N * 64 * 2);
    unsigned short* helu = (unsigned short*)alloc((size_t)N * 64 * 2);
    float* as1  = (float*)alloc((size_t)N * 8 * 4);
    float* ad1  = (float*)alloc((size_t)N * 8 * 4);
    int*   degv = (int*)alloc((size_t)N * 4);
    int*   offv = (int*)alloc((size_t)(N + 1) * 4);
    int*   csr  = (int*)alloc((size_t)E * 4);
    int*   histG  = (int*)alloc((size_t)nbuck * GCHUNK * 4);
    int*   startG = (int*)alloc((size_t)nbuck * GCHUNK * 4);
    int*   total  = (int*)alloc((size_t)nbuck * 4);
    int*   bbase  = (int*)alloc((size_t)(nbuck + 1) * 4);
    int*   pairbuf = (int*)alloc((size_t)E * 4);
    unsigned short* h2p = h1;   // reuse: h1 dead after agg1
    float* as2 = as1;
    float* ad2 = ad1;

    hipMemsetAsync(total, 0, (size_t)nbuck * 4, stream);
    hist_kernel<<<GCHUNK, 256, 0, stream>>>(dst, E, nbuck, histG, total);
    bscan_kernel<<<1, 1024, 0, stream>>>(total, bbase, nbuck);
    bstart_kernel<<<nbuck, 256, 0, stream>>>(histG, bbase, startG, nbuck);
    bucket_scatter<<<GCHUNK, 256, 0, stream>>>(src, dst, E, nbuck, startG, pairbuf);
    bucket_place<<<nbuck, 256, 0, stream>>>(pairbuf, bbase, nbuck, N, degv, offv, csr);

    int gb = (N + 127) / 128;
    gemm1_mfma<<<gb, 256, 0, stream>>>(x, W1, att_src1, att_dst1, h1, as1, ad1, N);
    agg1_kernel<<<(N + 7) / 8, 256, 0, stream>>>(h1, as1, ad1, offv, degv, csr, b1, helu, N);
    gemm2_mfma<<<gb, 256, 0, stream>>>(helu, W2, att_src2, att_dst2, h2p, as2, ad2, N);
    agg2_kernel<<<(N + 7) / 8, 256, 0, stream>>>(h2p, as2, ad2, offv, degv, csr, b2, out, N);
}

// Round 9
// 272.822 us; speedup vs baseline: 1.2656x; 1.0700x over previous
//
#include <hip/hip_runtime.h>
#include <math.h>

#define NEG_SLOPE 0.2f

typedef __attribute__((ext_vector_type(8))) short short8;
typedef __attribute__((ext_vector_type(4))) float f32x4;

__device__ __forceinline__ float leaky(float x) { return x > 0.f ? x : NEG_SLOPE * x; }

// fp32 -> bf16 (RNE)
__device__ __forceinline__ unsigned short f2bf(float f) {
    union { float f; unsigned u; } v; v.f = f;
    unsigned r = v.u + 0x7fffu + ((v.u >> 16) & 1u);
    return (unsigned short)(r >> 16);
}
__device__ __forceinline__ float bf2f(unsigned short s) {
    union { unsigned u; float f; } v; v.u = ((unsigned)s) << 16;
    return v.f;
}
__device__ __forceinline__ void unpack2(unsigned v, float& lo, float& hi) {
    union { unsigned u; float f; } a, b;
    a.u = v << 16; b.u = v & 0xffff0000u;
    lo = a.f; hi = b.f;
}
__device__ __forceinline__ unsigned pack2(float lo, float hi) {
    return (unsigned)f2bf(lo) | ((unsigned)f2bf(hi) << 16);
}

// ================= CSR build: workgroup-exclusive counting sort =================
#define GCHUNK 256
#define NB_MAX 1024   // supports N <= 131072

__global__ __launch_bounds__(256) void hist_kernel(const int* __restrict__ dst, int E, int nbuck,
                                                   int* __restrict__ histG, int* __restrict__ total) {
    __shared__ int lh[NB_MAX];
    int g = blockIdx.x, t = threadIdx.x;
    for (int i = t; i < nbuck; i += 256) lh[i] = 0;
    __syncthreads();
    int ce = (E + GCHUNK - 1) / GCHUNK;
    int e0 = g * ce, e1 = min(e0 + ce, E);
    for (int e = e0 + t; e < e1; e += 256)
        atomicAdd(&lh[dst[e] >> 7], 1);
    __syncthreads();
    for (int i = t; i < nbuck; i += 256) {
        histG[i * GCHUNK + g] = lh[i];
        if (lh[i]) atomicAdd(&total[i], lh[i]);
    }
}

__global__ __launch_bounds__(1024) void bscan_kernel(const int* __restrict__ total,
                                                     int* __restrict__ bbase, int nbuck) {
    __shared__ int sh[1024];
    int t = threadIdx.x;
    int v = (t < nbuck) ? total[t] : 0;
    sh[t] = v; __syncthreads();
    for (int s = 1; s < 1024; s <<= 1) {
        int add = (t >= s) ? sh[t - s] : 0;
        __syncthreads();
        sh[t] += add;
        __syncthreads();
    }
    if (t < nbuck) bbase[t] = sh[t] - v;
    if (t == nbuck - 1) bbase[nbuck] = sh[t];
}

__global__ __launch_bounds__(256) void bstart_kernel(const int* __restrict__ histG,
                                                     const int* __restrict__ bbase,
                                                     int* __restrict__ startG, int nbuck) {
    __shared__ int sh[256];
    int b = blockIdx.x, t = threadIdx.x;
    int v = histG[b * GCHUNK + t];
    sh[t] = v; __syncthreads();
    for (int s = 1; s < 256; s <<= 1) {
        int add = (t >= s) ? sh[t - s] : 0;
        __syncthreads();
        sh[t] += add;
        __syncthreads();
    }
    startG[b * GCHUNK + t] = bbase[b] + sh[t] - v;
}

__global__ __launch_bounds__(256) void bucket_scatter(const int* __restrict__ src,
                                                      const int* __restrict__ dst, int E, int nbuck,
                                                      const int* __restrict__ startG,
                                                      int* __restrict__ pairbuf) {
    __shared__ int cur[NB_MAX];
    int g = blockIdx.x, t = threadIdx.x;
    for (int i = t; i < nbuck; i += 256) cur[i] = startG[i * GCHUNK + g];
    __syncthreads();
    int ce = (E + GCHUNK - 1) / GCHUNK;
    int e0 = g * ce, e1 = min(e0 + ce, E);
    for (int e = e0 + t; e < e1; e += 256) {
        int d = dst[e], b = d >> 7;
        int pos = atomicAdd(&cur[b], 1);
        pairbuf[pos] = (src[e] << 7) | (d & 127);
    }
}

__global__ __launch_bounds__(256) void bucket_place(const int* __restrict__ pairbuf,
                                                    const int* __restrict__ bbase, int nbuck, int N,
                                                    int* __restrict__ deg, int* __restrict__ off,
                                                    int* __restrict__ csr) {
    __shared__ int stash[4096];
    __shared__ int ldeg[128], lcur[128], sh[128];
    int b = blockIdx.x, t = threadIdx.x;
    int p0 = bbase[b], p1 = bbase[b + 1];
    int cnt = p1 - p0;
    int node0 = b << 7;
    for (int i = t; i < 128; i += 256) ldeg[i] = 0;
    __syncthreads();
    for (int i = t; i < cnt; i += 256) {
        int pr = pairbuf[p0 + i];
        if (i < 4096) stash[i] = pr;
        atomicAdd(&ldeg[pr & 127], 1);
    }
    __syncthreads();
    if (t < 128) sh[t] = ldeg[t];
    __syncthreads();
    for (int s = 1; s < 128; s <<= 1) {
        int add = (t >= s && t < 128) ? sh[t - s] : 0;
        __syncthreads();
        if (t < 128) sh[t] += add;
        __syncthreads();
    }
    if (t < 128) {
        int excl = sh[t] - ldeg[t];
        int n = node0 + t;
        if (n < N) { deg[n] = ldeg[t]; off[n] = p0 + excl; }
        lcur[t] = p0 + excl;
    }
    __syncthreads();
    for (int i = t; i < cnt; i += 256) {
        int pr = (i < 4096) ? stash[i] : pairbuf[p0 + i];
        int pos = atomicAdd(&lcur[pr & 127], 1);
        csr[pos] = ((unsigned)pr) >> 7;
    }
}

// ---------------- GEMM1 (MFMA): h1 = bf16(x @ W1), dots in fp32 ----------------
// Epilogue is row-parallel: lane = (row = lane&31, half = lane>>5 covering 32 cols).
// Per-head dots fall entirely inside one lane's 32-col span -> no shfls.
__global__ __launch_bounds__(256) void gemm1_mfma(
    const float* __restrict__ x, const float* __restrict__ W1,
    const float* __restrict__ att_src, const float* __restrict__ att_dst,
    unsigned short* __restrict__ h1, float* __restrict__ a_src, float* __restrict__ a_dst, int N)
{
    __shared__ short Bl[16 * 64 * 8];   // 16 B-frags, 16 KB
    __shared__ float Cs[4][32 * 66];    // fp32 C stage, stride 66 (bank-spread), ~33 KB
    __shared__ float attL[128];         // [0..63]=att_src, [64..127]=att_dst
    int tid = threadIdx.x;
    if (tid < 128) attL[tid] = (tid < 64) ? att_src[tid] : att_dst[tid - 64];
    for (int f0 = tid; f0 < 1024; f0 += 256) {
        int lane = f0 & 63, s = (f0 >> 6) & 3, ct = f0 >> 8;
        int kb = s * 32 + ((lane >> 4) << 3);
        int col = ct * 16 + (lane & 15);
        short* dp = &Bl[f0 * 8];
#pragma unroll
        for (int j = 0; j < 8; ++j) dp[j] = (short)f2bf(W1[(kb + j) * 64 + col]);
    }
    __syncthreads();

    int lane = tid & 63, w = tid >> 6;
    int row0 = blockIdx.x * 128 + w * 32;
    if (row0 >= N) return;
    int ra = min(row0 + (lane & 15), N - 1);
    int rb = min(row0 + 16 + (lane & 15), N - 1);
    const float* pa = x + (size_t)ra * 128 + ((lane >> 4) << 3);
    const float* pb = x + (size_t)rb * 128 + ((lane >> 4) << 3);

    f32x4 acc[2][4];
#pragma unroll
    for (int i = 0; i < 2; ++i)
#pragma unroll
        for (int j = 0; j < 4; ++j) acc[i][j] = (f32x4){0.f, 0.f, 0.f, 0.f};

#pragma unroll
    for (int s = 0; s < 4; ++s) {
        float4 a0 = *(const float4*)(pa + s * 32);
        float4 a1 = *(const float4*)(pa + s * 32 + 4);
        float4 c0 = *(const float4*)(pb + s * 32);
        float4 c1 = *(const float4*)(pb + s * 32 + 4);
        short8 af, cf;
        af[0] = f2bf(a0.x); af[1] = f2bf(a0.y); af[2] = f2bf(a0.z); af[3] = f2bf(a0.w);
        af[4] = f2bf(a1.x); af[5] = f2bf(a1.y); af[6] = f2bf(a1.z); af[7] = f2bf(a1.w);
        cf[0] = f2bf(c0.x); cf[1] = f2bf(c0.y); cf[2] = f2bf(c0.z); cf[3] = f2bf(c0.w);
        cf[4] = f2bf(c1.x); cf[5] = f2bf(c1.y); cf[6] = f2bf(c1.z); cf[7] = f2bf(c1.w);
#pragma unroll
        for (int ct = 0; ct < 4; ++ct) {
            short8 wf = *(const short8*)&Bl[((ct * 4 + s) * 64 + lane) * 8];
            acc[0][ct] = __builtin_amdgcn_mfma_f32_16x16x32_bf16(af, wf, acc[0][ct], 0, 0, 0);
            acc[1][ct] = __builtin_amdgcn_mfma_f32_16x16x32_bf16(cf, wf, acc[1][ct], 0, 0, 0);
        }
    }

    float* cs = &Cs[w][0];
#pragma unroll
    for (int rt = 0; rt < 2; ++rt)
#pragma unroll
        for (int ct = 0; ct < 4; ++ct)
#pragma unroll
            for (int r = 0; r < 4; ++r) {
                int row = rt * 16 + ((lane >> 4) << 2) + r;
                int col = ct * 16 + (lane & 15);
                cs[row * 66 + col] = acc[rt][ct][r];
            }
    __syncthreads();

    // row-parallel epilogue: 2 lanes per row (32 cols each)
    int row = lane & 31, half = lane >> 5;
    const float* crow = cs + row * 66 + half * 32;
    const float* asl = attL + half * 32;
    const float* adl = attL + 64 + half * 32;
    float ds[4] = {0.f, 0.f, 0.f, 0.f};
    float es[4] = {0.f, 0.f, 0.f, 0.f};
    unsigned pk[16];
#pragma unroll
    for (int j = 0; j < 16; ++j) {
        float2 v = *(const float2*)(crow + 2 * j);
        float2 a = *(const float2*)(asl + 2 * j);
        float2 b = *(const float2*)(adl + 2 * j);
        int q = j >> 2;
        ds[q] = fmaf(v.x, a.x, fmaf(v.y, a.y, ds[q]));
        es[q] = fmaf(v.x, b.x, fmaf(v.y, b.y, es[q]));
        pk[j] = pack2(v.x, v.y);
    }
    int row_g = row0 + row;
    if (row_g < N) {
        uint4* hp = (uint4*)(h1 + (size_t)row_g * 64 + half * 32);
        hp[0] = make_uint4(pk[0], pk[1], pk[2], pk[3]);
        hp[1] = make_uint4(pk[4], pk[5], pk[6], pk[7]);
        hp[2] = make_uint4(pk[8], pk[9], pk[10], pk[11]);
        hp[3] = make_uint4(pk[12], pk[13], pk[14], pk[15]);
        *(float4*)(a_src + row_g * 8 + half * 4) = make_float4(ds[0], ds[1], ds[2], ds[3]);
        *(float4*)(a_dst + row_g * 8 + half * 4) = make_float4(es[0], es[1], es[2], es[3]);
    }
}

// ---------------- layer-1 aggregate: 2 nodes/wave, octet cols, 4-group unroll ----------------
__global__ __launch_bounds__(256) void agg1_kernel(
    const unsigned short* __restrict__ h1, const float* __restrict__ a_src, const float* __restrict__ a_dst,
    const int* __restrict__ off, const int* __restrict__ deg, const int* __restrict__ csr,
    const float* __restrict__ b1, unsigned short* __restrict__ helu, int N)
{
    int tid = threadIdx.x;
    int n = (blockIdx.x * 256 + tid) >> 5;
    int lane = tid & 63;
    int l32 = lane & 31;
    int hb = lane & 32;
    if (n >= N) return;
    int o = off[n], d = deg[n];
    int h8 = l32 & 7, g = l32 >> 3;

    float adst = a_dst[n * 8 + h8];
    float pself = __expf(leaky(a_src[n * 8 + h8] + adst));
    float s = (g == 0) ? pself : 0.f;

    float lo, hi;
    float acc0 = 0.f, acc1 = 0.f, acc2 = 0.f, acc3 = 0.f;
    float acc4 = 0.f, acc5 = 0.f, acc6 = 0.f, acc7 = 0.f;
    if (g == 0) {
        uint4 dvs = *(const uint4*)(h1 + (size_t)n * 64 + h8 * 8);
        unpack2(dvs.x, lo, hi); acc0 = pself * lo; acc1 = pself * hi;
        unpack2(dvs.y, lo, hi); acc2 = pself * lo; acc3 = pself * hi;
        unpack2(dvs.z, lo, hi); acc4 = pself * lo; acc5 = pself * hi;
        unpack2(dvs.w, lo, hi); acc6 = pself * lo; acc7 = pself * hi;
    }

#define A1_ACC(dv, p) \
    unpack2(dv.x, lo, hi); acc0 = fmaf(p, lo, acc0); acc1 = fmaf(p, hi, acc1); \
    unpack2(dv.y, lo, hi); acc2 = fmaf(p, lo, acc2); acc3 = fmaf(p, hi, acc3); \
    unpack2(dv.z, lo, hi); acc4 = fmaf(p, lo, acc4); acc5 = fmaf(p, hi, acc5); \
    unpack2(dv.w, lo, hi); acc6 = fmaf(p, lo, acc6); acc7 = fmaf(p, hi, acc7);

    for (int base = 0; base < d; base += 32) {
        int idx = base + l32;
        int sv = (idx < d) ? csr[o + idx] : 0;
        int lim = min(32, d - base);
        int tm = (lim + 3) >> 2;
        int t = 0;
        for (; t + 4 < tm; t += 4) {   // groups t..t+3 all provably full
            int e0 = t * 4 + g;
            int s0 = __shfl(sv, hb | e0), s1 = __shfl(sv, hb | (e0 + 4));
            int s2 = __shfl(sv, hb | (e0 + 8)), s3 = __shfl(sv, hb | (e0 + 12));
            float as0 = a_src[s0 * 8 + h8];
            float as1 = a_src[s1 * 8 + h8];
            float as2 = a_src[s2 * 8 + h8];
            float as3 = a_src[s3 * 8 + h8];
            uint4 d0 = *(const uint4*)(h1 + (size_t)s0 * 64 + h8 * 8);
            uint4 d1 = *(const uint4*)(h1 + (size_t)s1 * 64 + h8 * 8);
            uint4 d2 = *(const uint4*)(h1 + (size_t)s2 * 64 + h8 * 8);
            uint4 d3 = *(const uint4*)(h1 + (size_t)s3 * 64 + h8 * 8);
            float p0 = __expf(leaky(as0 + adst));
            float p1 = __expf(leaky(as1 + adst));
            float p2 = __expf(leaky(as2 + adst));
            float p3 = __expf(leaky(as3 + adst));
            s += (p0 + p1) + (p2 + p3);
            A1_ACC(d0, p0) A1_ACC(d1, p1) A1_ACC(d2, p2) A1_ACC(d3, p3)
        }
        for (; t + 1 < tm; t += 2) {   // group t full; group t+1 may be partial
            int e0 = t * 4 + g, e1 = e0 + 4;
            int s0 = __shfl(sv, hb | e0), s1 = __shfl(sv, hb | e1);
            float as0 = a_src[s0 * 8 + h8];
            float as1 = a_src[s1 * 8 + h8];
            uint4 d0 = *(const uint4*)(h1 + (size_t)s0 * 64 + h8 * 8);
            uint4 d1 = *(const uint4*)(h1 + (size_t)s1 * 64 + h8 * 8);
            float p0 = __expf(leaky(as0 + adst));
            float p1 = (e1 < lim) ? __expf(leaky(as1 + adst)) : 0.f;
            s += p0 + p1;
            A1_ACC(d0, p0) A1_ACC(d1, p1)
        }
        if (t < tm) {
            int e0 = t * 4 + g;
            int s0 = __shfl(sv, hb | e0);
            float as0 = a_src[s0 * 8 + h8];
            uint4 d0 = *(const uint4*)(h1 + (size_t)s0 * 64 + h8 * 8);
            float p0 = (e0 < lim) ? __expf(leaky(as0 + adst)) : 0.f;
            s += p0;
            A1_ACC(d0, p0)
        }
    }
#undef A1_ACC
    s += __shfl_xor(s, 8); s += __shfl_xor(s, 16);
    acc0 += __shfl_xor(acc0, 8); acc0 += __shfl_xor(acc0, 16);
    acc1 += __shfl_xor(acc1, 8); acc1 += __shfl_xor(acc1, 16);
    acc2 += __shfl_xor(acc2, 8); acc2 += __shfl_xor(acc2, 16);
    acc3 += __shfl_xor(acc3, 8); acc3 += __shfl_xor(acc3, 16);
    acc4 += __shfl_xor(acc4, 8); acc4 += __shfl_xor(acc4, 16);
    acc5 += __shfl_xor(acc5, 8); acc5 += __shfl_xor(acc5, 16);
    acc6 += __shfl_xor(acc6, 8); acc6 += __shfl_xor(acc6, 16);
    acc7 += __shfl_xor(acc7, 8); acc7 += __shfl_xor(acc7, 16);

    if (g == 0) {
        float r = 1.f / s;
        float4 bA = *(const float4*)(b1 + h8 * 8);
        float4 bB = *(const float4*)(b1 + h8 * 8 + 4);
        float v0 = acc0 * r + bA.x, v1 = acc1 * r + bA.y;
        float v2 = acc2 * r + bA.z, v3 = acc3 * r + bA.w;
        float v4 = acc4 * r + bB.x, v5 = acc5 * r + bB.y;
        float v6 = acc6 * r + bB.z, v7 = acc7 * r + bB.w;
        v0 = (v0 > 0.f) ? v0 : (__expf(v0) - 1.f);
        v1 = (v1 > 0.f) ? v1 : (__expf(v1) - 1.f);
        v2 = (v2 > 0.f) ? v2 : (__expf(v2) - 1.f);
        v3 = (v3 > 0.f) ? v3 : (__expf(v3) - 1.f);
        v4 = (v4 > 0.f) ? v4 : (__expf(v4) - 1.f);
        v5 = (v5 > 0.f) ? v5 : (__expf(v5) - 1.f);
        v6 = (v6 > 0.f) ? v6 : (__expf(v6) - 1.f);
        v7 = (v7 > 0.f) ? v7 : (__expf(v7) - 1.f);
        uint4 st;
        st.x = pack2(v0, v1);
        st.y = pack2(v2, v3);
        st.z = pack2(v4, v5);
        st.w = pack2(v6, v7);
        *(uint4*)(helu + (size_t)n * 64 + h8 * 8) = st;
    }
}

// -------- GEMM2 (MFMA): h2p = bf16(helu @ W2), rows PADDED to 64 cols --------
__global__ __launch_bounds__(256) void gemm2_mfma(
    const unsigned short* __restrict__ hin, const float* __restrict__ W2,
    const float* __restrict__ att_src2, const float* __restrict__ att_dst2,
    unsigned short* __restrict__ h2p, float* __restrict__ a_src, float* __restrict__ a_dst, int N)
{
    __shared__ short Bl[6 * 64 * 8];
    __shared__ float Cs[4][32 * 50];    // stride 50 (bank-spread), 25.6 KB
    __shared__ float attL[96];          // [0..47]=src (40+pad0), [48..95]=dst
    int tid = threadIdx.x;
    if (tid < 96) {
        int c = (tid < 48) ? tid : tid - 48;
        const float* sel = (tid < 48) ? att_src2 : att_dst2;
        attL[tid] = (c < 40) ? sel[c] : 0.f;
    }
    for (int f0 = tid; f0 < 384; f0 += 256) {
        int lane = f0 & 63; int fr = f0 >> 6; int s = fr & 1, ct = fr >> 1;
        int kb = s * 32 + ((lane >> 4) << 3);
        int col = ct * 16 + (lane & 15);
        short* dp = &Bl[f0 * 8];
#pragma unroll
        for (int j = 0; j < 8; ++j) dp[j] = (col < 40) ? (short)f2bf(W2[(kb + j) * 40 + col]) : (short)0;
    }
    __syncthreads();

    int lane = tid & 63, w = tid >> 6;
    int row0 = blockIdx.x * 128 + w * 32;
    if (row0 >= N) return;
    int ra = min(row0 + (lane & 15), N - 1);
    int rb = min(row0 + 16 + (lane & 15), N - 1);
    const unsigned short* pa = hin + (size_t)ra * 64 + ((lane >> 4) << 3);
    const unsigned short* pb = hin + (size_t)rb * 64 + ((lane >> 4) << 3);

    f32x4 acc[2][3];
#pragma unroll
    for (int i = 0; i < 2; ++i)
#pragma unroll
        for (int j = 0; j < 3; ++j) acc[i][j] = (f32x4){0.f, 0.f, 0.f, 0.f};

#pragma unroll
    for (int s = 0; s < 2; ++s) {
        short8 af = *(const short8*)(pa + s * 32);
        short8 cf = *(const short8*)(pb + s * 32);
#pragma unroll
        for (int ct = 0; ct < 3; ++ct) {
            short8 wf = *(const short8*)&Bl[((ct * 2 + s) * 64 + lane) * 8];
            acc[0][ct] = __builtin_amdgcn_mfma_f32_16x16x32_bf16(af, wf, acc[0][ct], 0, 0, 0);
            acc[1][ct] = __builtin_amdgcn_mfma_f32_16x16x32_bf16(cf, wf, acc[1][ct], 0, 0, 0);
        }
    }

    float* cs = &Cs[w][0];
#pragma unroll
    for (int rt = 0; rt < 2; ++rt)
#pragma unroll
        for (int ct = 0; ct < 3; ++ct)
#pragma unroll
            for (int r = 0; r < 4; ++r) {
                int row = rt * 16 + ((lane >> 4) << 2) + r;
                int col = ct * 16 + (lane & 15);
                cs[row * 50 + col] = acc[rt][ct][r];
            }
    __syncthreads();

    // row-parallel epilogue: lane = (row, half); half covers 24 cols
    int row = lane & 31, half = lane >> 5;
    const float* crow = cs + row * 50 + half * 24;
    const float* asl = attL + half * 24;
    const float* adl = attL + 48 + half * 24;
    float dsum = 0.f, esum = 0.f;
    unsigned pk[12];
#pragma unroll
    for (int j = 0; j < 12; ++j) {
        float2 v = *(const float2*)(crow + 2 * j);
        float2 a = *(const float2*)(asl + 2 * j);
        float2 b = *(const float2*)(adl + 2 * j);
        dsum = fmaf(v.x, a.x, fmaf(v.y, a.y, dsum));
        esum = fmaf(v.x, b.x, fmaf(v.y, b.y, esum));
        pk[j] = pack2(v.x, v.y);
    }
    dsum += __shfl_xor(dsum, 32);
    esum += __shfl_xor(esum, 32);
    int row_g = row0 + row;
    if (row_g < N) {
        unsigned short* hr = h2p + (size_t)row_g * 64;
        if (half == 0) {
            uint4* hp = (uint4*)hr;
            hp[0] = make_uint4(pk[0], pk[1], pk[2], pk[3]);
            hp[1] = make_uint4(pk[4], pk[5], pk[6], pk[7]);
            hp[2] = make_uint4(pk[8], pk[9], pk[10], pk[11]);
            a_src[row_g] = dsum;
            a_dst[row_g] = esum;
        } else {
            uint4* hp = (uint4*)(hr + 24);
            hp[0] = make_uint4(pk[0], pk[1], pk[2], pk[3]);
            hp[1] = make_uint4(pk[4], pk[5], pk[6], pk[7]);
            hp[2] = make_uint4(pk[8], pk[9], pk[10], pk[11]);
            uint4* zp = (uint4*)(hr + 48);
            zp[0] = make_uint4(0, 0, 0, 0);
            zp[1] = make_uint4(0, 0, 0, 0);
        }
    }
}

// ---------------- layer-2 aggregate: 2 nodes/wave, 4-group unroll, + log_softmax ----------------
__global__ __launch_bounds__(256) void agg2_kernel(
    const unsigned short* __restrict__ h2p, const float* __restrict__ a_src, const float* __restrict__ a_dst,
    const int* __restrict__ off, const int* __restrict__ deg, const int* __restrict__ csr,
    const float* __restrict__ b2, float* __restrict__ out, int N)
{
    int tid = threadIdx.x;
    int n = (blockIdx.x * 256 + tid) >> 5;
    int lane = tid & 63;
    int l32 = lane & 31;
    int hb = lane & 32;
    if (n >= N) return;
    int o = off[n], d = deg[n];
    int h8 = l32 & 7, g = l32 >> 3;

    float adst = a_dst[n];
    float pself = __expf(leaky(a_src[n] + adst));
    float sp = (g == 0) ? pself : 0.f;

    float lo, hi;
    float acc0 = 0.f, acc1 = 0.f, acc2 = 0.f, acc3 = 0.f;
    float acc4 = 0.f, acc5 = 0.f, acc6 = 0.f, acc7 = 0.f;
    if (g == 0) {
        uint4 dvs = *(const uint4*)(h2p + (size_t)n * 64 + h8 * 8);
        unpack2(dvs.x, lo, hi); acc0 = pself * lo; acc1 = pself * hi;
        unpack2(dvs.y, lo, hi); acc2 = pself * lo; acc3 = pself * hi;
        unpack2(dvs.z, lo, hi); acc4 = pself * lo; acc5 = pself * hi;
        unpack2(dvs.w, lo, hi); acc6 = pself * lo; acc7 = pself * hi;
    }

#define A2_ACC(dv, p) \
    unpack2(dv.x, lo, hi); acc0 = fmaf(p, lo, acc0); acc1 = fmaf(p, hi, acc1); \
    unpack2(dv.y, lo, hi); acc2 = fmaf(p, lo, acc2); acc3 = fmaf(p, hi, acc3); \
    unpack2(dv.z, lo, hi); acc4 = fmaf(p, lo, acc4); acc5 = fmaf(p, hi, acc5); \
    unpack2(dv.w, lo, hi); acc6 = fmaf(p, lo, acc6); acc7 = fmaf(p, hi, acc7);

    for (int base = 0; base < d; base += 32) {
        int idx = base + l32;
        int sv = (idx < d) ? csr[o + idx] : 0;
        int lim = min(32, d - base);
        int tm = (lim + 3) >> 2;
        int t = 0;
        for (; t + 4 < tm; t += 4) {
            int e0 = t * 4 + g;
            int s0 = __shfl(sv, hb | e0), s1 = __shfl(sv, hb | (e0 + 4));
            int s2 = __shfl(sv, hb | (e0 + 8)), s3 = __shfl(sv, hb | (e0 + 12));
            float as0 = a_src[s0];
            float as1 = a_src[s1];
            float as2 = a_src[s2];
            float as3 = a_src[s3];
            uint4 d0 = *(const uint4*)(h2p + (size_t)s0 * 64 + h8 * 8);
            uint4 d1 = *(const uint4*)(h2p + (size_t)s1 * 64 + h8 * 8);
            uint4 d2 = *(const uint4*)(h2p + (size_t)s2 * 64 + h8 * 8);
            uint4 d3 = *(const uint4*)(h2p + (size_t)s3 * 64 + h8 * 8);
            float p0 = __expf(leaky(as0 + adst));
            float p1 = __expf(leaky(as1 + adst));
            float p2 = __expf(leaky(as2 + adst));
            float p3 = __expf(leaky(as3 + adst));
            sp += (p0 + p1) + (p2 + p3);
            A2_ACC(d0, p0) A2_ACC(d1, p1) A2_ACC(d2, p2) A2_ACC(d3, p3)
        }
        for (; t + 1 < tm; t += 2) {
            int e0 = t * 4 + g, e1 = e0 + 4;
            int s0 = __shfl(sv, hb | e0), s1 = __shfl(sv, hb | e1);
            float as0 = a_src[s0];
            float as1 = a_src[s1];
            uint4 d0 = *(const uint4*)(h2p + (size_t)s0 * 64 + h8 * 8);
            uint4 d1 = *(const uint4*)(h2p + (size_t)s1 * 64 + h8 * 8);
            float p0 = __expf(leaky(as0 + adst));
            float p1 = (e1 < lim) ? __expf(leaky(as1 + adst)) : 0.f;
            sp += p0 + p1;
            A2_ACC(d0, p0) A2_ACC(d1, p1)
        }
        if (t < tm) {
            int e0 = t * 4 + g;
            int s0 = __shfl(sv, hb | e0);
            float as0 = a_src[s0];
            uint4 d0 = *(const uint4*)(h2p + (size_t)s0 * 64 + h8 * 8);
            float p0 = (e0 < lim) ? __expf(leaky(as0 + adst)) : 0.f;
            sp += p0;
            A2_ACC(d0, p0)
        }
    }
#undef A2_ACC
    sp += __shfl_xor(sp, 8); sp += __shfl_xor(sp, 16);
    acc0 += __shfl_xor(acc0, 8); acc0 += __shfl_xor(acc0, 16);
    acc1 += __shfl_xor(acc1, 8); acc1 += __shfl_xor(acc1, 16);
    acc2 += __shfl_xor(acc2, 8); acc2 += __shfl_xor(acc2, 16);
    acc3 += __shfl_xor(acc3, 8); acc3 += __shfl_xor(acc3, 16);
    acc4 += __shfl_xor(acc4, 8); acc4 += __shfl_xor(acc4, 16);
    acc5 += __shfl_xor(acc5, 8); acc5 += __shfl_xor(acc5, 16);
    acc6 += __shfl_xor(acc6, 8); acc6 += __shfl_xor(acc6, 16);
    acc7 += __shfl_xor(acc7, 8); acc7 += __shfl_xor(acc7, 16);

    if (g == 0) {
        float r = 1.f / sp;
        float v0 = -INFINITY, v1 = -INFINITY, v2 = -INFINITY, v3 = -INFINITY;
        float v4 = -INFINITY, v5 = -INFINITY, v6 = -INFINITY, v7 = -INFINITY;
        if (h8 < 5) {
            float4 bA = *(const float4*)(b2 + h8 * 8);
            float4 bB = *(const float4*)(b2 + h8 * 8 + 4);
            v0 = acc0 * r + bA.x; v1 = acc1 * r + bA.y;
            v2 = acc2 * r + bA.z; v3 = acc3 * r + bA.w;
            v4 = acc4 * r + bB.x; v5 = acc5 * r + bB.y;
            v6 = acc6 * r + bB.z; v7 = acc7 * r + bB.w;
        }
        float mx = fmaxf(fmaxf(fmaxf(v0, v1), fmaxf(v2, v3)), fmaxf(fmaxf(v4, v5), fmaxf(v6, v7)));
        mx = fmaxf(mx, __shfl_xor(mx, 1));
        mx = fmaxf(mx, __shfl_xor(mx, 2));
        mx = fmaxf(mx, __shfl_xor(mx, 4));
        float se = 0.f;
        if (h8 < 5)
            se = __expf(v0 - mx) + __expf(v1 - mx) + __expf(v2 - mx) + __expf(v3 - mx)
               + __expf(v4 - mx) + __expf(v5 - mx) + __expf(v6 - mx) + __expf(v7 - mx);
        se += __shfl_xor(se, 1); se += __shfl_xor(se, 2); se += __shfl_xor(se, 4);
        if (h8 < 5) {
            float ls = mx + logf(se);
            float* op = out + (size_t)n * 40 + h8 * 8;
            *(float4*)op = make_float4(v0 - ls, v1 - ls, v2 - ls, v3 - ls);
            *(float4*)(op + 4) = make_float4(v4 - ls, v5 - ls, v6 - ls, v7 - ls);
        }
    }
}

extern "C" void kernel_launch(void* const* d_in, const int* in_sizes, int n_in,
                              void* d_out, int out_size, void* d_ws, size_t ws_size,
                              hipStream_t stream) {
    const float* x        = (const float*)d_in[0];
    const int*   ei       = (const int*)d_in[1];
    const float* W1       = (const float*)d_in[2];
    const float* att_src1 = (const float*)d_in[3];
    const float* att_dst1 = (const float*)d_in[4];
    const float* b1       = (const float*)d_in[5];
    const float* W2       = (const float*)d_in[6];
    const float* att_src2 = (const float*)d_in[7];
    const float* att_dst2 = (const float*)d_in[8];
    const float* b2       = (const float*)d_in[9];
    float* out = (float*)d_out;

    int N = in_sizes[0] / 128;
    int E = in_sizes[1] / 2;
    const int* src = ei;
    const int* dst = ei + E;
    int nbuck = (N + 127) >> 7;

    char* w = (char*)d_ws;
    auto alloc = [&](size_t bytes) { void* p = (void*)w; w += (bytes + 255) & ~(size_t)255; return p; };
    unsigned short* h1   = (unsigned short*)alloc((size_t)N * 64 * 2);
    unsigned short* helu = (unsigned short*)alloc((size_t)N * 64 * 2);
    float* as1  = (float*)alloc((size_t)N * 8 * 4);
    float* ad1  = (float*)alloc((size_t)N * 8 * 4);
    int*   degv = (int*)alloc((size_t)N * 4);
    int*   offv = (int*)alloc((size_t)(N + 1) * 4);
    int*   csr  = (int*)alloc((size_t)E * 4);
    int*   histG  = (int*)alloc((size_t)nbuck * GCHUNK * 4);
    int*   startG = (int*)alloc((size_t)nbuck * GCHUNK * 4);
    int*   total  = (int*)alloc((size_t)nbuck * 4);
    int*   bbase  = (int*)alloc((size_t)(nbuck + 1) * 4);
    int*   pairbuf = (int*)alloc((size_t)E * 4);
    unsigned short* h2p = h1;   // reuse: h1 dead after agg1
    float* as2 = as1;
    float* ad2 = ad1;

    hipMemsetAsync(total, 0, (size_t)nbuck * 4, stream);
    hist_kernel<<<GCHUNK, 256, 0, stream>>>(dst, E, nbuck, histG, total);
    bscan_kernel<<<1, 1024, 0, stream>>>(total, bbase, nbuck);
    bstart_kernel<<<nbuck, 256, 0, stream>>>(histG, bbase, startG, nbuck);
    bucket_scatter<<<GCHUNK, 256, 0, stream>>>(src, dst, E, nbuck, startG, pairbuf);
    bucket_place<<<nbuck, 256, 0, stream>>>(pairbuf, bbase, nbuck, N, degv, offv, csr);

    int gb = (N + 127) / 128;
    gemm1_mfma<<<gb, 256, 0, stream>>>(x, W1, att_src1, att_dst1, h1, as1, ad1, N);
    agg1_kernel<<<(N + 7) / 8, 256, 0, stream>>>(h1, as1, ad1, offv, degv, csr, b1, helu, N);
    gemm2_mfma<<<gb, 256, 0, stream>>>(helu, W2, att_src2, att_dst2, h2p, as2, ad2, N);
    agg2_kernel<<<(N + 7) / 8, 256, 0, stream>>>(h2p, as2, ad2, offv, degv, csr, b2, out, N);
}